// Round 3
// baseline (606.523 us; speedup 1.0000x reference)
//
#include <hip/hip_runtime.h>
#include <math.h>

#define NFEAT 128
#define NHID 64
#define NCLASS 40
#define NSHADOW 8

// ---------------------------------------------------------------------------
// chunk-privatized histograms: deg_s[c][src], hist_s[c][dst] for edge-chunk c
// ---------------------------------------------------------------------------
__global__ void hist_shadow_kernel(const int* __restrict__ src,
                                   const int* __restrict__ dst, int E, int n,
                                   int* __restrict__ deg_s,
                                   int* __restrict__ hist_s) {
    int bpc = gridDim.x / NSHADOW;
    int chunk = blockIdx.x / bpc;
    int bidin = blockIdx.x - chunk * bpc;
    int c0 = (int)((long long)E * chunk / NSHADOW);
    int c1 = (int)((long long)E * (chunk + 1) / NSHADOW);
    int* __restrict__ degc = deg_s + (size_t)chunk * n;
    int* __restrict__ histc = hist_s + (size_t)chunk * n;
    int stride = bpc * blockDim.x;
    for (int e = c0 + bidin * blockDim.x + threadIdx.x; e < c1; e += stride) {
        atomicAdd(&degc[src[e]], 1);
        atomicAdd(&histc[dst[e]], 1);
    }
}

// deg = 1 + sum_c deg_s ; dinv = rsqrt(deg) ; htot = sum_c hist_s
__global__ void reduce_kernel(const int* __restrict__ deg_s,
                              const int* __restrict__ hist_s,
                              float* __restrict__ dinv,
                              int* __restrict__ htot, int n) {
    int i = blockIdx.x * blockDim.x + threadIdx.x;
    if (i >= n) return;
    int d = 1, h = 0;
#pragma unroll
    for (int s = 0; s < NSHADOW; ++s) {
        d += deg_s[(size_t)s * n + i];
        h += hist_s[(size_t)s * n + i];
    }
    dinv[i] = rsqrtf((float)d);
    htot[i] = h;
}

// ---------------------------------------------------------------------------
// exclusive scan of htot[n] -> row_start[n+1]  (3 kernels)
// ---------------------------------------------------------------------------
__global__ void scan_block_kernel(const int* __restrict__ hist,
                                  int* __restrict__ scanned,
                                  int* __restrict__ bsums, int n) {
    __shared__ int tmp[256];
    int i = blockIdx.x * 256 + threadIdx.x;
    int v = (i < n) ? hist[i] : 0;
    tmp[threadIdx.x] = v;
    __syncthreads();
#pragma unroll
    for (int off = 1; off < 256; off <<= 1) {
        int t = (threadIdx.x >= off) ? tmp[threadIdx.x - off] : 0;
        __syncthreads();
        tmp[threadIdx.x] += t;
        __syncthreads();
    }
    if (i < n) scanned[i] = tmp[threadIdx.x] - v;  // exclusive
    if (threadIdx.x == 255) bsums[blockIdx.x] = tmp[255];
}

__global__ void scan_partials_kernel(int* __restrict__ bsums, int nb) {
    __shared__ int tmp[512];
    int v = (threadIdx.x < nb) ? bsums[threadIdx.x] : 0;
    tmp[threadIdx.x] = v;
    __syncthreads();
#pragma unroll
    for (int off = 1; off < 512; off <<= 1) {
        int t = (threadIdx.x >= off) ? tmp[threadIdx.x - off] : 0;
        __syncthreads();
        tmp[threadIdx.x] += t;
        __syncthreads();
    }
    if (threadIdx.x < nb) bsums[threadIdx.x] = tmp[threadIdx.x] - v;  // exclusive
}

__global__ void scan_add_kernel(const int* __restrict__ scanned,
                                const int* __restrict__ bsums,
                                int* __restrict__ row_start, int n, int E) {
    int i = blockIdx.x * 256 + threadIdx.x;
    if (i < n) row_start[i] = scanned[i] + bsums[blockIdx.x];
    if (i == 0) row_start[n] = E;
}

// per-chunk cursor bases: cursor[c][i] = row_start[i] + sum_{t<c} hist_s[t][i]
__global__ void base_kernel(const int* __restrict__ row_start,
                            const int* __restrict__ hist_s,
                            int* __restrict__ cursor, int n) {
    int i = blockIdx.x * blockDim.x + threadIdx.x;
    if (i >= n) return;
    int r = row_start[i];
#pragma unroll
    for (int s = 0; s < NSHADOW; ++s) {
        cursor[(size_t)s * n + i] = r;
        r += hist_s[(size_t)s * n + i];
    }
}

// ---------------------------------------------------------------------------
// scatter: counting-sort edges by dst with per-chunk cursors, pack {src, norm}
// ---------------------------------------------------------------------------
__global__ void scatter_shadow_kernel(const int* __restrict__ src,
                                      const int* __restrict__ dst,
                                      const float* __restrict__ dinv,
                                      int* __restrict__ cursor,
                                      int2* __restrict__ es, int E, int n) {
    int bpc = gridDim.x / NSHADOW;
    int chunk = blockIdx.x / bpc;
    int bidin = blockIdx.x - chunk * bpc;
    int c0 = (int)((long long)E * chunk / NSHADOW);
    int c1 = (int)((long long)E * (chunk + 1) / NSHADOW);
    int* __restrict__ cur = cursor + (size_t)chunk * n;
    int stride = bpc * blockDim.x;
    for (int e = c0 + bidin * blockDim.x + threadIdx.x; e < c1; e += stride) {
        int s = src[e], d = dst[e];
        int pos = atomicAdd(&cur[d], 1);
        es[pos] = make_int2(s, __float_as_int(dinv[s] * dinv[d]));
    }
}

// ---------------------------------------------------------------------------
// H1 = x @ W1 + b1    (M=100000, K=128, N=64)  one wave per node
// ---------------------------------------------------------------------------
__global__ __launch_bounds__(256) void gemm1_kernel(
    const float* __restrict__ x, const float* __restrict__ W1,
    const float* __restrict__ b1, float* __restrict__ H1, int n) {
    __shared__ float Wl[NFEAT * NHID];   // 32 KB
    __shared__ float xr[4][NFEAT];       // 2 KB
    for (int t = threadIdx.x; t < NFEAT * NHID; t += 256) Wl[t] = W1[t];
    __syncthreads();
    int wave = threadIdx.x >> 6;
    int lane = threadIdx.x & 63;
    float bias = b1[lane];
    int stride = gridDim.x * 4;
    for (int node = blockIdx.x * 4 + wave; node < n; node += stride) {
        xr[wave][lane]      = x[(size_t)node * NFEAT + lane];
        xr[wave][lane + 64] = x[(size_t)node * NFEAT + 64 + lane];
        float acc = bias;
#pragma unroll
        for (int k = 0; k < NFEAT; ++k)
            acc += xr[wave][k] * Wl[k * NHID + lane];
        H1[(size_t)node * NHID + lane] = acc;
    }
}

// ---------------------------------------------------------------------------
// fused layer-1 aggregation (gather over CSR) + self-loop + ReLU + GEMM2
// ---------------------------------------------------------------------------
__global__ __launch_bounds__(256) void agg1_gemm2_kernel(
    const int2* __restrict__ es, const int* __restrict__ row_start,
    const float* __restrict__ dinv, const float* __restrict__ H1,
    const float* __restrict__ W2, const float* __restrict__ b2,
    float* __restrict__ H2, int n) {
    __shared__ float W2l[NHID * NCLASS];  // 10 KB
    __shared__ float rl[4][NHID];
    for (int t = threadIdx.x; t < NHID * NCLASS; t += 256) W2l[t] = W2[t];
    __syncthreads();
    int wave = threadIdx.x >> 6;
    int lane = threadIdx.x & 63;
    int stride = gridDim.x * 4;
    for (int node = blockIdx.x * 4 + wave; node < n; node += stride) {
        int e0 = row_start[node], e1 = row_start[node + 1];
        float acc = 0.f;
        int e = e0;
        for (; e + 1 < e1; e += 2) {
            int2 p0 = es[e];
            int2 p1 = es[e + 1];
            float v0 = H1[(size_t)p0.x * NHID + lane];
            float v1 = H1[(size_t)p1.x * NHID + lane];
            acc += __int_as_float(p0.y) * v0 + __int_as_float(p1.y) * v1;
        }
        if (e < e1) {
            int2 p = es[e];
            acc += __int_as_float(p.y) * H1[(size_t)p.x * NHID + lane];
        }
        float di = dinv[node];
        acc += di * di * H1[(size_t)node * NHID + lane];  // self-loop
        rl[wave][lane] = fmaxf(acc, 0.f);
        if (lane < NCLASS) {
            float a2 = b2[lane];
#pragma unroll
            for (int h = 0; h < NHID; ++h)
                a2 += rl[wave][h] * W2l[h * NCLASS + lane];
            H2[(size_t)node * NCLASS + lane] = a2;
        }
    }
}

// ---------------------------------------------------------------------------
// fused layer-2 aggregation + self-loop + log_softmax -> out
// ---------------------------------------------------------------------------
__global__ __launch_bounds__(256) void agg2_lsm_kernel(
    const int2* __restrict__ es, const int* __restrict__ row_start,
    const float* __restrict__ dinv, const float* __restrict__ H2,
    float* __restrict__ out, int n) {
    int wave = threadIdx.x >> 6;
    int lane = threadIdx.x & 63;
    bool act = lane < NCLASS;
    int stride = gridDim.x * 4;
    for (int node = blockIdx.x * 4 + wave; node < n; node += stride) {
        int e0 = row_start[node], e1 = row_start[node + 1];
        float acc = 0.f;
        int e = e0;
        for (; e + 1 < e1; e += 2) {
            int2 p0 = es[e];
            int2 p1 = es[e + 1];
            if (act) {
                acc += __int_as_float(p0.y) * H2[(size_t)p0.x * NCLASS + lane]
                     + __int_as_float(p1.y) * H2[(size_t)p1.x * NCLASS + lane];
            }
        }
        if (e < e1) {
            int2 p = es[e];
            if (act) acc += __int_as_float(p.y) * H2[(size_t)p.x * NCLASS + lane];
        }
        float di = dinv[node];
        float val = 0.f, v = -INFINITY;
        if (act) {
            val = acc + di * di * H2[(size_t)node * NCLASS + lane];
            v = val;
        }
#pragma unroll
        for (int off = 32; off; off >>= 1) v = fmaxf(v, __shfl_xor(v, off, 64));
        float ex = act ? expf(val - v) : 0.f;
#pragma unroll
        for (int off = 32; off; off >>= 1) ex += __shfl_xor(ex, off, 64);
        float lse = logf(ex) + v;
        if (act) out[(size_t)node * NCLASS + lane] = val - lse;
    }
}

// ---------------------------------------------------------------------------
extern "C" void kernel_launch(void* const* d_in, const int* in_sizes, int n_in,
                              void* d_out, int out_size, void* d_ws, size_t ws_size,
                              hipStream_t stream) {
    const float* x  = (const float*)d_in[0];
    const int*   ei = (const int*)d_in[1];
    const float* W1 = (const float*)d_in[2];
    const float* b1 = (const float*)d_in[3];
    const float* W2 = (const float*)d_in[4];
    const float* b2 = (const float*)d_in[5];
    float* out = (float*)d_out;

    const int n = in_sizes[0] / NFEAT;       // 100000
    const int E = in_sizes[1] / 2;           // 1600000
    const int* src = ei;
    const int* dst = ei + E;

    const size_t nb = (size_t)n * 4;         // 400 KB

    // workspace layout (bytes)
    char* ws = (char*)d_ws;
    float* dinv      = (float*)(ws + 0);
    int*   htot      = (int*)(ws + (512 << 10));
    int*   scanned   = (int*)(ws + (1024 << 10));
    int*   row_start = (int*)(ws + (1536 << 10));
    int*   bsums     = (int*)(ws + (2048 << 10));
    int*   deg_s     = (int*)(ws + (3u << 20));                 // 8*n ints = 3.2 MB
    int*   hist_s    = (int*)(ws + (3u << 20) + NSHADOW * nb);  // 8*n ints = 3.2 MB
    int*   cursor    = deg_s;  // alias: deg_s dead after reduce_kernel
    int2*  es        = (int2*)(ws + (3u << 20) + 2 * NSHADOW * nb + (1u << 20)); // 12.8 MB
    float* H1        = (float*)(ws + (24u << 20));              // 25.6 MB
    float* H2        = (float*)(ws + (50u << 20));              // 16 MB

    const int blk = 256;
    const int nblk_n = (n + blk - 1) / blk;  // 391

    hipMemsetAsync(deg_s, 0, 2 * NSHADOW * nb, stream);  // deg_s + hist_s contiguous
    hist_shadow_kernel<<<2048, blk, 0, stream>>>(src, dst, E, n, deg_s, hist_s);
    reduce_kernel<<<nblk_n, blk, 0, stream>>>(deg_s, hist_s, dinv, htot, n);

    scan_block_kernel<<<nblk_n, blk, 0, stream>>>(htot, scanned, bsums, n);
    scan_partials_kernel<<<1, 512, 0, stream>>>(bsums, nblk_n);
    scan_add_kernel<<<nblk_n, blk, 0, stream>>>(scanned, bsums, row_start, n, E);
    base_kernel<<<nblk_n, blk, 0, stream>>>(row_start, hist_s, cursor, n);

    scatter_shadow_kernel<<<2048, blk, 0, stream>>>(src, dst, dinv, cursor, es, E, n);

    gemm1_kernel<<<2048, blk, 0, stream>>>(x, W1, b1, H1, n);

    agg1_gemm2_kernel<<<4096, blk, 0, stream>>>(es, row_start, dinv, H1, W2, b2, H2, n);

    agg2_lsm_kernel<<<4096, blk, 0, stream>>>(es, row_start, dinv, H2, out, n);
}

// Round 4
// 582.381 us; speedup vs baseline: 1.0415x; 1.0415x over previous
//
#include <hip/hip_runtime.h>
#include <hip/hip_fp16.h>
#include <math.h>

#define NFEAT 128
#define NHID 64
#define NCLASS 40
#define NCHUNK 32
#define RANGE 16384   // nodes per LDS range (7 ranges cover 100k)

// ---------------------------------------------------------------------------
// LDS-binned deg(src) + hist(dst), packed 2xu16 counters, no global atomics.
// grid = NCHUNK * nrange blocks; block (c, r) bins edge-slice c into range r.
// Writes ushort partials deg_p[c][n], hist_p[c][n] with plain stores.
// ---------------------------------------------------------------------------
__global__ __launch_bounds__(256) void histdeg_kernel(
    const int* __restrict__ src, const int* __restrict__ dst, int E, int n,
    int nrange, unsigned short* __restrict__ deg_p,
    unsigned short* __restrict__ hist_p) {
    __shared__ unsigned int degc[RANGE / 2];   // 32 KB
    __shared__ unsigned int histc[RANGE / 2];  // 32 KB
    int c = blockIdx.x / nrange;
    int r = blockIdx.x - c * nrange;
    int r0 = r * RANGE;
    for (int i = threadIdx.x; i < RANGE / 2; i += 256) {
        degc[i] = 0u;
        histc[i] = 0u;
    }
    __syncthreads();
    int e0 = (int)((long long)E * c / NCHUNK);
    int e1 = (int)((long long)E * (c + 1) / NCHUNK);
    for (int e = e0 + threadIdx.x; e < e1; e += 256) {
        int s = src[e] - r0;
        int d = dst[e] - r0;
        if ((unsigned)s < (unsigned)RANGE)
            atomicAdd(&degc[s >> 1], 1u << ((s & 1) * 16));
        if ((unsigned)d < (unsigned)RANGE)
            atomicAdd(&histc[d >> 1], 1u << ((d & 1) * 16));
    }
    __syncthreads();
    int hi = n - r0; if (hi > RANGE) hi = RANGE;
    for (int i = threadIdx.x; i < hi; i += 256) {
        unsigned dv = (degc[i >> 1] >> ((i & 1) * 16)) & 0xFFFFu;
        unsigned hv = (histc[i >> 1] >> ((i & 1) * 16)) & 0xFFFFu;
        deg_p[(size_t)c * n + r0 + i] = (unsigned short)dv;
        hist_p[(size_t)c * n + r0 + i] = (unsigned short)hv;
    }
}

// deg = 1 + sum_c deg_p ; dinv = rsqrt(deg) ; htot = sum_c hist_p
__global__ void reduce_kernel(const unsigned short* __restrict__ deg_p,
                              const unsigned short* __restrict__ hist_p,
                              float* __restrict__ dinv,
                              int* __restrict__ htot, int n) {
    int i = blockIdx.x * blockDim.x + threadIdx.x;
    if (i >= n) return;
    int d = 1, h = 0;
#pragma unroll
    for (int c = 0; c < NCHUNK; ++c) {
        d += deg_p[(size_t)c * n + i];
        h += hist_p[(size_t)c * n + i];
    }
    dinv[i] = rsqrtf((float)d);
    htot[i] = h;
}

// ---------------------------------------------------------------------------
// exclusive scan of htot[n] -> row_start[n+1]  (3 kernels)
// ---------------------------------------------------------------------------
__global__ void scan_block_kernel(const int* __restrict__ hist,
                                  int* __restrict__ scanned,
                                  int* __restrict__ bsums, int n) {
    __shared__ int tmp[256];
    int i = blockIdx.x * 256 + threadIdx.x;
    int v = (i < n) ? hist[i] : 0;
    tmp[threadIdx.x] = v;
    __syncthreads();
#pragma unroll
    for (int off = 1; off < 256; off <<= 1) {
        int t = (threadIdx.x >= off) ? tmp[threadIdx.x - off] : 0;
        __syncthreads();
        tmp[threadIdx.x] += t;
        __syncthreads();
    }
    if (i < n) scanned[i] = tmp[threadIdx.x] - v;  // exclusive
    if (threadIdx.x == 255) bsums[blockIdx.x] = tmp[255];
}

__global__ void scan_partials_kernel(int* __restrict__ bsums, int nb) {
    __shared__ int tmp[512];
    int v = (threadIdx.x < nb) ? bsums[threadIdx.x] : 0;
    tmp[threadIdx.x] = v;
    __syncthreads();
#pragma unroll
    for (int off = 1; off < 512; off <<= 1) {
        int t = (threadIdx.x >= off) ? tmp[threadIdx.x - off] : 0;
        __syncthreads();
        tmp[threadIdx.x] += t;
        __syncthreads();
    }
    if (threadIdx.x < nb) bsums[threadIdx.x] = tmp[threadIdx.x] - v;  // exclusive
}

__global__ void scan_add_kernel(const int* __restrict__ scanned,
                                const int* __restrict__ bsums,
                                int* __restrict__ row_start, int n, int E) {
    int i = blockIdx.x * 256 + threadIdx.x;
    if (i < n) row_start[i] = scanned[i] + bsums[blockIdx.x];
    if (i == 0) row_start[n] = E;
}

// per-chunk cursor bases: bases[c][i] = row_start[i] + sum_{t<c} hist_p[t][i]
__global__ void base_kernel(const int* __restrict__ row_start,
                            const unsigned short* __restrict__ hist_p,
                            int* __restrict__ bases, int n) {
    int i = blockIdx.x * blockDim.x + threadIdx.x;
    if (i >= n) return;
    int r = row_start[i];
#pragma unroll
    for (int c = 0; c < NCHUNK; ++c) {
        bases[(size_t)c * n + i] = r;
        r += hist_p[(size_t)c * n + i];
    }
}

// ---------------------------------------------------------------------------
// scatter: counting-sort edge srcs by dst; cursors live in LDS (no global
// atomics). es[pos] = src only — norm is factorized into H1'/H2' and dinv[d].
// ---------------------------------------------------------------------------
__global__ __launch_bounds__(256) void scatter_kernel(
    const int* __restrict__ src, const int* __restrict__ dst, int E, int n,
    int nrange, const int* __restrict__ bases, int* __restrict__ es) {
    __shared__ int cur[RANGE];  // 64 KB
    int c = blockIdx.x / nrange;
    int r = blockIdx.x - c * nrange;
    int r0 = r * RANGE;
    int hi = n - r0; if (hi > RANGE) hi = RANGE;
    for (int i = threadIdx.x; i < hi; i += 256)
        cur[i] = bases[(size_t)c * n + r0 + i];
    __syncthreads();
    int e0 = (int)((long long)E * c / NCHUNK);
    int e1 = (int)((long long)E * (c + 1) / NCHUNK);
    for (int e = e0 + threadIdx.x; e < e1; e += 256) {
        int d = dst[e] - r0;
        if ((unsigned)d < (unsigned)hi) {
            int pos = atomicAdd(&cur[d], 1);
            es[pos] = src[e];
        }
    }
}

// ---------------------------------------------------------------------------
// H1' = dinv * (x @ W1 + b1) stored fp16   (one wave per node)
// ---------------------------------------------------------------------------
__global__ __launch_bounds__(256) void gemm1_kernel(
    const float* __restrict__ x, const float* __restrict__ W1,
    const float* __restrict__ b1, const float* __restrict__ dinv,
    __half* __restrict__ H1h, int n) {
    __shared__ float Wl[NFEAT * NHID];   // 32 KB
    __shared__ float xr[4][NFEAT];
    for (int t = threadIdx.x; t < NFEAT * NHID; t += 256) Wl[t] = W1[t];
    __syncthreads();
    int wave = threadIdx.x >> 6;
    int lane = threadIdx.x & 63;
    float bias = b1[lane];
    int stride = gridDim.x * 4;
    for (int node = blockIdx.x * 4 + wave; node < n; node += stride) {
        xr[wave][lane]      = x[(size_t)node * NFEAT + lane];
        xr[wave][lane + 64] = x[(size_t)node * NFEAT + 64 + lane];
        float acc = bias;
#pragma unroll
        for (int k = 0; k < NFEAT; ++k)
            acc += xr[wave][k] * Wl[k * NHID + lane];
        H1h[(size_t)node * NHID + lane] = __float2half_rn(acc * dinv[node]);
    }
}

// ---------------------------------------------------------------------------
// fused: agg1 (gather-sum of H1' rows, scale by dinv[d]) + ReLU + GEMM2
// writes H2' = dinv * (relu(...) @ W2 + b2) fp16
// ---------------------------------------------------------------------------
__global__ __launch_bounds__(256) void agg1_gemm2_kernel(
    const int* __restrict__ es, const int* __restrict__ row_start,
    const float* __restrict__ dinv, const __half* __restrict__ H1h,
    const float* __restrict__ W2, const float* __restrict__ b2,
    __half* __restrict__ H2h, int n) {
    __shared__ float W2l[NHID * NCLASS];  // 10 KB
    __shared__ float rl[4][NHID];
    for (int t = threadIdx.x; t < NHID * NCLASS; t += 256) W2l[t] = W2[t];
    __syncthreads();
    int wave = threadIdx.x >> 6;
    int lane = threadIdx.x & 63;
    int stride = gridDim.x * 4;
    for (int node = blockIdx.x * 4 + wave; node < n; node += stride) {
        int e0 = row_start[node], e1 = row_start[node + 1];
        float acc = __half2float(H1h[(size_t)node * NHID + lane]);  // self-loop
        int e = e0;
        for (; e + 1 < e1; e += 2) {
            int s0 = es[e], s1 = es[e + 1];
            float v0 = __half2float(H1h[(size_t)s0 * NHID + lane]);
            float v1 = __half2float(H1h[(size_t)s1 * NHID + lane]);
            acc += v0 + v1;
        }
        if (e < e1) acc += __half2float(H1h[(size_t)es[e] * NHID + lane]);
        float di = dinv[node];
        rl[wave][lane] = fmaxf(acc * di, 0.f);
        if (lane < NCLASS) {
            float a2 = b2[lane];
#pragma unroll
            for (int h = 0; h < NHID; ++h)
                a2 += rl[wave][h] * W2l[h * NCLASS + lane];
            H2h[(size_t)node * NCLASS + lane] = __float2half_rn(a2 * di);
        }
    }
}

// ---------------------------------------------------------------------------
// fused: agg2 (gather-sum of H2' rows, scale by dinv[d]) + log_softmax
// ---------------------------------------------------------------------------
__global__ __launch_bounds__(256) void agg2_lsm_kernel(
    const int* __restrict__ es, const int* __restrict__ row_start,
    const float* __restrict__ dinv, const __half* __restrict__ H2h,
    float* __restrict__ out, int n) {
    int wave = threadIdx.x >> 6;
    int lane = threadIdx.x & 63;
    bool act = lane < NCLASS;
    int stride = gridDim.x * 4;
    for (int node = blockIdx.x * 4 + wave; node < n; node += stride) {
        int e0 = row_start[node], e1 = row_start[node + 1];
        float acc = act ? __half2float(H2h[(size_t)node * NCLASS + lane]) : 0.f;
        int e = e0;
        for (; e + 1 < e1; e += 2) {
            int s0 = es[e], s1 = es[e + 1];
            if (act) {
                acc += __half2float(H2h[(size_t)s0 * NCLASS + lane])
                     + __half2float(H2h[(size_t)s1 * NCLASS + lane]);
            }
        }
        if (e < e1) {
            int s = es[e];
            if (act) acc += __half2float(H2h[(size_t)s * NCLASS + lane]);
        }
        float val = 0.f, v = -INFINITY;
        if (act) {
            val = acc * dinv[node];
            v = val;
        }
#pragma unroll
        for (int off = 32; off; off >>= 1) v = fmaxf(v, __shfl_xor(v, off, 64));
        float ex = act ? expf(val - v) : 0.f;
#pragma unroll
        for (int off = 32; off; off >>= 1) ex += __shfl_xor(ex, off, 64);
        float lse = logf(ex) + v;
        if (act) out[(size_t)node * NCLASS + lane] = val - lse;
    }
}

// ---------------------------------------------------------------------------
extern "C" void kernel_launch(void* const* d_in, const int* in_sizes, int n_in,
                              void* d_out, int out_size, void* d_ws, size_t ws_size,
                              hipStream_t stream) {
    const float* x  = (const float*)d_in[0];
    const int*   ei = (const int*)d_in[1];
    const float* W1 = (const float*)d_in[2];
    const float* b1 = (const float*)d_in[3];
    const float* W2 = (const float*)d_in[4];
    const float* b2 = (const float*)d_in[5];
    float* out = (float*)d_out;

    const int n = in_sizes[0] / NFEAT;       // 100000
    const int E = in_sizes[1] / 2;           // 1600000
    const int* src = ei;
    const int* dst = ei + E;
    const int nrange = (n + RANGE - 1) / RANGE;  // 7

    // workspace layout (byte offsets); every array is fully written before
    // read, so no memsets are needed.
    char* ws = (char*)d_ws;
    float*          dinv      = (float*)(ws + 0);                  // 400 KB
    int*            htot      = (int*)(ws + (512 << 10));
    int*            scanned   = (int*)(ws + (1024 << 10));
    int*            row_start = (int*)(ws + (1536 << 10));
    int*            bsums     = (int*)(ws + (2048 << 10));
    unsigned short* deg_p     = (unsigned short*)(ws + (3u << 20));   // 6.4 MB
    unsigned short* hist_p    = (unsigned short*)(ws + (10u << 20));  // 6.4 MB
    int*            bases     = (int*)(ws + (17u << 20));             // 12.8 MB
    int*            es        = (int*)(ws + (30u << 20));             // 6.4 MB
    __half*         H1h       = (__half*)(ws + (37u << 20));          // 12.8 MB
    __half*         H2h       = (__half*)(ws + (50u << 20));          // 8 MB

    const int blk = 256;
    const int nblk_n = (n + blk - 1) / blk;  // 391
    const int gridbin = NCHUNK * nrange;     // 224

    histdeg_kernel<<<gridbin, blk, 0, stream>>>(src, dst, E, n, nrange, deg_p, hist_p);
    reduce_kernel<<<nblk_n, blk, 0, stream>>>(deg_p, hist_p, dinv, htot, n);

    scan_block_kernel<<<nblk_n, blk, 0, stream>>>(htot, scanned, bsums, n);
    scan_partials_kernel<<<1, 512, 0, stream>>>(bsums, nblk_n);
    scan_add_kernel<<<nblk_n, blk, 0, stream>>>(scanned, bsums, row_start, n, E);
    base_kernel<<<nblk_n, blk, 0, stream>>>(row_start, hist_p, bases, n);

    scatter_kernel<<<gridbin, blk, 0, stream>>>(src, dst, E, n, nrange, bases, es);

    gemm1_kernel<<<2048, blk, 0, stream>>>(x, W1, b1, dinv, H1h, n);

    agg1_gemm2_kernel<<<4096, blk, 0, stream>>>(es, row_start, dinv, H1h, W2, b2, H2h, n);

    agg2_lsm_kernel<<<4096, blk, 0, stream>>>(es, row_start, dinv, H2h, out, n);
}

// Round 5
// 480.535 us; speedup vs baseline: 1.2622x; 1.2119x over previous
//
#include <hip/hip_runtime.h>
#include <hip/hip_fp16.h>
#include <math.h>

#define NFEAT 128
#define NHID 64
#define NCLASS 40
#define NCHUNK 32
#define RANGE 16384   // nodes per LDS range (7 ranges cover 100k)

// ---------------------------------------------------------------------------
// LDS-binned deg(src) + hist(dst), packed 2xu16 counters, no global atomics.
// ---------------------------------------------------------------------------
__global__ __launch_bounds__(256) void histdeg_kernel(
    const int* __restrict__ src, const int* __restrict__ dst, int E, int n,
    int nrange, unsigned short* __restrict__ deg_p,
    unsigned short* __restrict__ hist_p) {
    __shared__ unsigned int degc[RANGE / 2];   // 32 KB
    __shared__ unsigned int histc[RANGE / 2];  // 32 KB
    int c = blockIdx.x / nrange;
    int r = blockIdx.x - c * nrange;
    int r0 = r * RANGE;
    for (int i = threadIdx.x; i < RANGE / 2; i += 256) {
        degc[i] = 0u;
        histc[i] = 0u;
    }
    __syncthreads();
    int e0 = (int)((long long)E * c / NCHUNK);
    int e1 = (int)((long long)E * (c + 1) / NCHUNK);
    for (int e = e0 + threadIdx.x; e < e1; e += 256) {
        int s = src[e] - r0;
        int d = dst[e] - r0;
        if ((unsigned)s < (unsigned)RANGE)
            atomicAdd(&degc[s >> 1], 1u << ((s & 1) * 16));
        if ((unsigned)d < (unsigned)RANGE)
            atomicAdd(&histc[d >> 1], 1u << ((d & 1) * 16));
    }
    __syncthreads();
    int hi = n - r0; if (hi > RANGE) hi = RANGE;
    for (int i = threadIdx.x; i < hi; i += 256) {
        unsigned dv = (degc[i >> 1] >> ((i & 1) * 16)) & 0xFFFFu;
        unsigned hv = (histc[i >> 1] >> ((i & 1) * 16)) & 0xFFFFu;
        deg_p[(size_t)c * n + r0 + i] = (unsigned short)dv;
        hist_p[(size_t)c * n + r0 + i] = (unsigned short)hv;
    }
}

// deg = 1 + sum_c deg_p ; dinv = rsqrt(deg) ; htot = sum_c hist_p
__global__ void reduce_kernel(const unsigned short* __restrict__ deg_p,
                              const unsigned short* __restrict__ hist_p,
                              float* __restrict__ dinv,
                              int* __restrict__ htot, int n) {
    int i = blockIdx.x * blockDim.x + threadIdx.x;
    if (i >= n) return;
    int d = 1, h = 0;
#pragma unroll
    for (int c = 0; c < NCHUNK; ++c) {
        d += deg_p[(size_t)c * n + i];
        h += hist_p[(size_t)c * n + i];
    }
    dinv[i] = rsqrtf((float)d);
    htot[i] = h;
}

// ---------------------------------------------------------------------------
// exclusive scan of htot[n] -> row_start[n+1]  (3 kernels)
// ---------------------------------------------------------------------------
__global__ void scan_block_kernel(const int* __restrict__ hist,
                                  int* __restrict__ scanned,
                                  int* __restrict__ bsums, int n) {
    __shared__ int tmp[256];
    int i = blockIdx.x * 256 + threadIdx.x;
    int v = (i < n) ? hist[i] : 0;
    tmp[threadIdx.x] = v;
    __syncthreads();
#pragma unroll
    for (int off = 1; off < 256; off <<= 1) {
        int t = (threadIdx.x >= off) ? tmp[threadIdx.x - off] : 0;
        __syncthreads();
        tmp[threadIdx.x] += t;
        __syncthreads();
    }
    if (i < n) scanned[i] = tmp[threadIdx.x] - v;  // exclusive
    if (threadIdx.x == 255) bsums[blockIdx.x] = tmp[255];
}

__global__ void scan_partials_kernel(int* __restrict__ bsums, int nb) {
    __shared__ int tmp[512];
    int v = (threadIdx.x < nb) ? bsums[threadIdx.x] : 0;
    tmp[threadIdx.x] = v;
    __syncthreads();
#pragma unroll
    for (int off = 1; off < 512; off <<= 1) {
        int t = (threadIdx.x >= off) ? tmp[threadIdx.x - off] : 0;
        __syncthreads();
        tmp[threadIdx.x] += t;
        __syncthreads();
    }
    if (threadIdx.x < nb) bsums[threadIdx.x] = tmp[threadIdx.x] - v;  // exclusive
}

__global__ void scan_add_kernel(const int* __restrict__ scanned,
                                const int* __restrict__ bsums,
                                int* __restrict__ row_start, int n, int E) {
    int i = blockIdx.x * 256 + threadIdx.x;
    if (i < n) row_start[i] = scanned[i] + bsums[blockIdx.x];
    if (i == 0) row_start[n] = E;
}

// per-chunk cursor bases: bases[c][i] = row_start[i] + sum_{t<c} hist_p[t][i]
__global__ void base_kernel(const int* __restrict__ row_start,
                            const unsigned short* __restrict__ hist_p,
                            int* __restrict__ bases, int n) {
    int i = blockIdx.x * blockDim.x + threadIdx.x;
    if (i >= n) return;
    int r = row_start[i];
#pragma unroll
    for (int c = 0; c < NCHUNK; ++c) {
        bases[(size_t)c * n + i] = r;
        r += hist_p[(size_t)c * n + i];
    }
}

// ---------------------------------------------------------------------------
// scatter: counting-sort edge srcs by dst; cursors live in LDS.
// ---------------------------------------------------------------------------
__global__ __launch_bounds__(256) void scatter_kernel(
    const int* __restrict__ src, const int* __restrict__ dst, int E, int n,
    int nrange, const int* __restrict__ bases, int* __restrict__ es) {
    __shared__ int cur[RANGE];  // 64 KB
    int c = blockIdx.x / nrange;
    int r = blockIdx.x - c * nrange;
    int r0 = r * RANGE;
    int hi = n - r0; if (hi > RANGE) hi = RANGE;
    for (int i = threadIdx.x; i < hi; i += 256)
        cur[i] = bases[(size_t)c * n + r0 + i];
    __syncthreads();
    int e0 = (int)((long long)E * c / NCHUNK);
    int e1 = (int)((long long)E * (c + 1) / NCHUNK);
    for (int e = e0 + threadIdx.x; e < e1; e += 256) {
        int d = dst[e] - r0;
        if ((unsigned)d < (unsigned)hi) {
            int pos = atomicAdd(&cur[d], 1);
            es[pos] = src[e];
        }
    }
}

// ---------------------------------------------------------------------------
// H1' = dinv * (x @ W1 + b1) stored fp16   (one wave per node)
// ---------------------------------------------------------------------------
__global__ __launch_bounds__(256) void gemm1_kernel(
    const float* __restrict__ x, const float* __restrict__ W1,
    const float* __restrict__ b1, const float* __restrict__ dinv,
    __half* __restrict__ H1h, int n) {
    __shared__ float Wl[NFEAT * NHID];   // 32 KB
    __shared__ float xr[4][NFEAT];
    for (int t = threadIdx.x; t < NFEAT * NHID; t += 256) Wl[t] = W1[t];
    __syncthreads();
    int wave = threadIdx.x >> 6;
    int lane = threadIdx.x & 63;
    float bias = b1[lane];
    int stride = gridDim.x * 4;
    for (int node = blockIdx.x * 4 + wave; node < n; node += stride) {
        xr[wave][lane]      = x[(size_t)node * NFEAT + lane];
        xr[wave][lane + 64] = x[(size_t)node * NFEAT + 64 + lane];
        float acc = bias;
#pragma unroll
        for (int k = 0; k < NFEAT; ++k)
            acc += xr[wave][k] * Wl[k * NHID + lane];
        H1h[(size_t)node * NHID + lane] = __float2half_rn(acc * dinv[node]);
    }
}

// ---------------------------------------------------------------------------
// fused: agg1 (gather-sum of H1' rows) + ReLU + GEMM2 -> H2' fp16
// 64-edge batched es load + shfl distribution + 8-deep independent gathers
// ---------------------------------------------------------------------------
__global__ __launch_bounds__(256) void agg1_gemm2_kernel(
    const int* __restrict__ es, const int* __restrict__ row_start,
    const float* __restrict__ dinv, const __half* __restrict__ H1h,
    const float* __restrict__ W2, const float* __restrict__ b2,
    __half* __restrict__ H2h, int n) {
    __shared__ float W2l[NHID * NCLASS];  // 10 KB
    __shared__ float rl[4][NHID];
    for (int t = threadIdx.x; t < NHID * NCLASS; t += 256) W2l[t] = W2[t];
    __syncthreads();
    int wave = threadIdx.x >> 6;
    int lane = threadIdx.x & 63;
    float bias2 = (lane < NCLASS) ? b2[lane] : 0.f;
    int stride = gridDim.x * 4;
    for (int node = blockIdx.x * 4 + wave; node < n; node += stride) {
        int e0 = row_start[node], e1 = row_start[node + 1];
        float acc = __half2float(H1h[(size_t)node * NHID + lane]);  // self-loop
        for (int e = e0; e < e1; e += 64) {
            int cnt = e1 - e; if (cnt > 64) cnt = 64;
            int myE = es[e + ((lane < cnt) ? lane : 0)];  // one coalesced load
            int j = 0;
            for (; j + 8 <= cnt; j += 8) {
                int s0 = __shfl(myE, j, 64), s1 = __shfl(myE, j + 1, 64);
                int s2 = __shfl(myE, j + 2, 64), s3 = __shfl(myE, j + 3, 64);
                int s4 = __shfl(myE, j + 4, 64), s5 = __shfl(myE, j + 5, 64);
                int s6 = __shfl(myE, j + 6, 64), s7 = __shfl(myE, j + 7, 64);
                __half v0 = H1h[(size_t)s0 * NHID + lane];
                __half v1 = H1h[(size_t)s1 * NHID + lane];
                __half v2 = H1h[(size_t)s2 * NHID + lane];
                __half v3 = H1h[(size_t)s3 * NHID + lane];
                __half v4 = H1h[(size_t)s4 * NHID + lane];
                __half v5 = H1h[(size_t)s5 * NHID + lane];
                __half v6 = H1h[(size_t)s6 * NHID + lane];
                __half v7 = H1h[(size_t)s7 * NHID + lane];
                acc += __half2float(v0) + __half2float(v1) + __half2float(v2) +
                       __half2float(v3) + __half2float(v4) + __half2float(v5) +
                       __half2float(v6) + __half2float(v7);
            }
            for (; j < cnt; ++j) {
                int s = __shfl(myE, j, 64);
                acc += __half2float(H1h[(size_t)s * NHID + lane]);
            }
        }
        float di = dinv[node];
        rl[wave][lane] = fmaxf(acc * di, 0.f);
        if (lane < NCLASS) {
            float a2 = bias2;
#pragma unroll
            for (int h = 0; h < NHID; ++h)
                a2 += rl[wave][h] * W2l[h * NCLASS + lane];
            H2h[(size_t)node * NCLASS + lane] = __float2half_rn(a2 * di);
        }
    }
}

// ---------------------------------------------------------------------------
// fused: agg2 (gather-sum of H2' rows) + log_softmax -> out
// same batched-ILP structure; all 64 lanes load es, lanes 0..39 gather rows
// ---------------------------------------------------------------------------
__global__ __launch_bounds__(256) void agg2_lsm_kernel(
    const int* __restrict__ es, const int* __restrict__ row_start,
    const float* __restrict__ dinv, const __half* __restrict__ H2h,
    float* __restrict__ out, int n) {
    int wave = threadIdx.x >> 6;
    int lane = threadIdx.x & 63;
    bool act = lane < NCLASS;
    int cl = act ? lane : 0;  // safe column for inactive lanes
    int stride = gridDim.x * 4;
    for (int node = blockIdx.x * 4 + wave; node < n; node += stride) {
        int e0 = row_start[node], e1 = row_start[node + 1];
        float acc = __half2float(H2h[(size_t)node * NCLASS + cl]);  // self-loop
        for (int e = e0; e < e1; e += 64) {
            int cnt = e1 - e; if (cnt > 64) cnt = 64;
            int myE = es[e + ((lane < cnt) ? lane : 0)];
            int j = 0;
            for (; j + 8 <= cnt; j += 8) {
                int s0 = __shfl(myE, j, 64), s1 = __shfl(myE, j + 1, 64);
                int s2 = __shfl(myE, j + 2, 64), s3 = __shfl(myE, j + 3, 64);
                int s4 = __shfl(myE, j + 4, 64), s5 = __shfl(myE, j + 5, 64);
                int s6 = __shfl(myE, j + 6, 64), s7 = __shfl(myE, j + 7, 64);
                __half v0 = H2h[(size_t)s0 * NCLASS + cl];
                __half v1 = H2h[(size_t)s1 * NCLASS + cl];
                __half v2 = H2h[(size_t)s2 * NCLASS + cl];
                __half v3 = H2h[(size_t)s3 * NCLASS + cl];
                __half v4 = H2h[(size_t)s4 * NCLASS + cl];
                __half v5 = H2h[(size_t)s5 * NCLASS + cl];
                __half v6 = H2h[(size_t)s6 * NCLASS + cl];
                __half v7 = H2h[(size_t)s7 * NCLASS + cl];
                acc += __half2float(v0) + __half2float(v1) + __half2float(v2) +
                       __half2float(v3) + __half2float(v4) + __half2float(v5) +
                       __half2float(v6) + __half2float(v7);
            }
            for (; j < cnt; ++j) {
                int s = __shfl(myE, j, 64);
                acc += __half2float(H2h[(size_t)s * NCLASS + cl]);
            }
        }
        float val = 0.f, v = -INFINITY;
        if (act) {
            val = acc * dinv[node];
            v = val;
        }
#pragma unroll
        for (int off = 32; off; off >>= 1) v = fmaxf(v, __shfl_xor(v, off, 64));
        float ex = act ? expf(val - v) : 0.f;
#pragma unroll
        for (int off = 32; off; off >>= 1) ex += __shfl_xor(ex, off, 64);
        float lse = logf(ex) + v;
        if (act) out[(size_t)node * NCLASS + lane] = val - lse;
    }
}

// ---------------------------------------------------------------------------
extern "C" void kernel_launch(void* const* d_in, const int* in_sizes, int n_in,
                              void* d_out, int out_size, void* d_ws, size_t ws_size,
                              hipStream_t stream) {
    const float* x  = (const float*)d_in[0];
    const int*   ei = (const int*)d_in[1];
    const float* W1 = (const float*)d_in[2];
    const float* b1 = (const float*)d_in[3];
    const float* W2 = (const float*)d_in[4];
    const float* b2 = (const float*)d_in[5];
    float* out = (float*)d_out;

    const int n = in_sizes[0] / NFEAT;       // 100000
    const int E = in_sizes[1] / 2;           // 1600000
    const int* src = ei;
    const int* dst = ei + E;
    const int nrange = (n + RANGE - 1) / RANGE;  // 7

    char* ws = (char*)d_ws;
    float*          dinv      = (float*)(ws + 0);
    int*            htot      = (int*)(ws + (512 << 10));
    int*            scanned   = (int*)(ws + (1024 << 10));
    int*            row_start = (int*)(ws + (1536 << 10));
    int*            bsums     = (int*)(ws + (2048 << 10));
    unsigned short* deg_p     = (unsigned short*)(ws + (3u << 20));   // 6.4 MB
    unsigned short* hist_p    = (unsigned short*)(ws + (10u << 20));  // 6.4 MB
    int*            bases     = (int*)(ws + (17u << 20));             // 12.8 MB
    int*            es        = (int*)(ws + (30u << 20));             // 6.4 MB
    __half*         H1h       = (__half*)(ws + (37u << 20));          // 12.8 MB
    __half*         H2h       = (__half*)(ws + (50u << 20));          // 8 MB

    const int blk = 256;
    const int nblk_n = (n + blk - 1) / blk;  // 391
    const int gridbin = NCHUNK * nrange;     // 224

    histdeg_kernel<<<gridbin, blk, 0, stream>>>(src, dst, E, n, nrange, deg_p, hist_p);
    reduce_kernel<<<nblk_n, blk, 0, stream>>>(deg_p, hist_p, dinv, htot, n);

    scan_block_kernel<<<nblk_n, blk, 0, stream>>>(htot, scanned, bsums, n);
    scan_partials_kernel<<<1, 512, 0, stream>>>(bsums, nblk_n);
    scan_add_kernel<<<nblk_n, blk, 0, stream>>>(scanned, bsums, row_start, n, E);
    base_kernel<<<nblk_n, blk, 0, stream>>>(row_start, hist_p, bases, n);

    scatter_kernel<<<gridbin, blk, 0, stream>>>(src, dst, E, n, nrange, bases, es);

    gemm1_kernel<<<2048, blk, 0, stream>>>(x, W1, b1, dinv, H1h, n);

    agg1_gemm2_kernel<<<4096, blk, 0, stream>>>(es, row_start, dinv, H1h, W2, b2, H2h, n);

    agg2_lsm_kernel<<<4096, blk, 0, stream>>>(es, row_start, dinv, H2h, out, n);
}

// Round 6
// 346.441 us; speedup vs baseline: 1.7507x; 1.3871x over previous
//
#include <hip/hip_runtime.h>
#include <hip/hip_fp16.h>
#include <math.h>

#define NFEAT 128
#define NHID 64
#define NCLASS 40
#define NCHUNK 64
#define RANGE 16384   // nodes per LDS range (7 ranges cover 100k)

// ---------------------------------------------------------------------------
// LDS-binned deg(src) + hist(dst), packed 2xu16 counters, no global atomics.
// 1024-thread blocks, 64KB LDS -> 2 blocks/CU (32 waves). int4 edge loads.
// ---------------------------------------------------------------------------
__global__ __launch_bounds__(1024) void histdeg_kernel(
    const int* __restrict__ src, const int* __restrict__ dst, int E, int n,
    int nrange, unsigned short* __restrict__ deg_p,
    unsigned short* __restrict__ hist_p) {
    __shared__ unsigned int degc[RANGE / 2];   // 32 KB
    __shared__ unsigned int histc[RANGE / 2];  // 32 KB
    int c = blockIdx.x / nrange;
    int r = blockIdx.x - c * nrange;
    int r0 = r * RANGE;
    for (int i = threadIdx.x; i < RANGE / 2; i += 1024) {
        degc[i] = 0u;
        histc[i] = 0u;
    }
    __syncthreads();
    int e0 = (int)((long long)E * c / NCHUNK);
    int e1 = (int)((long long)E * (c + 1) / NCHUNK);
    for (int e = e0 + threadIdx.x * 4; e + 4 <= e1; e += 4096) {
        int4 s4 = *(const int4*)(src + e);
        int4 d4 = *(const int4*)(dst + e);
        int ss[4] = {s4.x, s4.y, s4.z, s4.w};
        int dd[4] = {d4.x, d4.y, d4.z, d4.w};
#pragma unroll
        for (int k = 0; k < 4; ++k) {
            int s = ss[k] - r0, d = dd[k] - r0;
            if ((unsigned)s < (unsigned)RANGE)
                atomicAdd(&degc[s >> 1], 1u << ((s & 1) * 16));
            if ((unsigned)d < (unsigned)RANGE)
                atomicAdd(&histc[d >> 1], 1u << ((d & 1) * 16));
        }
    }
    int tb = e0 + ((e1 - e0) & ~3);  // scalar tail
    for (int e = tb + threadIdx.x; e < e1; e += 1024) {
        int s = src[e] - r0, d = dst[e] - r0;
        if ((unsigned)s < (unsigned)RANGE)
            atomicAdd(&degc[s >> 1], 1u << ((s & 1) * 16));
        if ((unsigned)d < (unsigned)RANGE)
            atomicAdd(&histc[d >> 1], 1u << ((d & 1) * 16));
    }
    __syncthreads();
    int hi = n - r0; if (hi > RANGE) hi = RANGE;
    for (int i = threadIdx.x; i < hi; i += 1024) {
        unsigned dv = (degc[i >> 1] >> ((i & 1) * 16)) & 0xFFFFu;
        unsigned hv = (histc[i >> 1] >> ((i & 1) * 16)) & 0xFFFFu;
        deg_p[(size_t)c * n + r0 + i] = (unsigned short)dv;
        hist_p[(size_t)c * n + r0 + i] = (unsigned short)hv;
    }
}

// deg = 1 + sum_c deg_p ; dinv = rsqrt(deg) ; htot = sum_c hist_p
__global__ void reduce_kernel(const unsigned short* __restrict__ deg_p,
                              const unsigned short* __restrict__ hist_p,
                              float* __restrict__ dinv,
                              int* __restrict__ htot, int n) {
    int i = blockIdx.x * blockDim.x + threadIdx.x;
    if (i >= n) return;
    int d = 1, h = 0;
#pragma unroll 8
    for (int c = 0; c < NCHUNK; ++c) {
        d += deg_p[(size_t)c * n + i];
        h += hist_p[(size_t)c * n + i];
    }
    dinv[i] = rsqrtf((float)d);
    htot[i] = h;
}

// ---------------------------------------------------------------------------
// exclusive scan of htot[n] -> row_start[n+1]  (3 kernels)
// ---------------------------------------------------------------------------
__global__ void scan_block_kernel(const int* __restrict__ hist,
                                  int* __restrict__ scanned,
                                  int* __restrict__ bsums, int n) {
    __shared__ int tmp[256];
    int i = blockIdx.x * 256 + threadIdx.x;
    int v = (i < n) ? hist[i] : 0;
    tmp[threadIdx.x] = v;
    __syncthreads();
#pragma unroll
    for (int off = 1; off < 256; off <<= 1) {
        int t = (threadIdx.x >= off) ? tmp[threadIdx.x - off] : 0;
        __syncthreads();
        tmp[threadIdx.x] += t;
        __syncthreads();
    }
    if (i < n) scanned[i] = tmp[threadIdx.x] - v;  // exclusive
    if (threadIdx.x == 255) bsums[blockIdx.x] = tmp[255];
}

__global__ void scan_partials_kernel(int* __restrict__ bsums, int nb) {
    __shared__ int tmp[512];
    int v = (threadIdx.x < nb) ? bsums[threadIdx.x] : 0;
    tmp[threadIdx.x] = v;
    __syncthreads();
#pragma unroll
    for (int off = 1; off < 512; off <<= 1) {
        int t = (threadIdx.x >= off) ? tmp[threadIdx.x - off] : 0;
        __syncthreads();
        tmp[threadIdx.x] += t;
        __syncthreads();
    }
    if (threadIdx.x < nb) bsums[threadIdx.x] = tmp[threadIdx.x] - v;  // exclusive
}

__global__ void scan_add_kernel(const int* __restrict__ scanned,
                                const int* __restrict__ bsums,
                                int* __restrict__ row_start, int n, int E) {
    int i = blockIdx.x * 256 + threadIdx.x;
    if (i < n) row_start[i] = scanned[i] + bsums[blockIdx.x];
    if (i == 0) row_start[n] = E;
}

// per-chunk cursor bases: bases[c][i] = row_start[i] + sum_{t<c} hist_p[t][i]
__global__ void base_kernel(const int* __restrict__ row_start,
                            const unsigned short* __restrict__ hist_p,
                            int* __restrict__ bases, int n) {
    int i = blockIdx.x * blockDim.x + threadIdx.x;
    if (i >= n) return;
    int r = row_start[i];
#pragma unroll 8
    for (int c = 0; c < NCHUNK; ++c) {
        bases[(size_t)c * n + i] = r;
        r += hist_p[(size_t)c * n + i];
    }
}

// ---------------------------------------------------------------------------
// scatter: counting-sort edge srcs by dst; cursors in LDS; int4 edge loads.
// 1024-thread blocks, 64KB LDS -> 2 blocks/CU.
// ---------------------------------------------------------------------------
__global__ __launch_bounds__(1024) void scatter_kernel(
    const int* __restrict__ src, const int* __restrict__ dst, int E, int n,
    int nrange, const int* __restrict__ bases, int* __restrict__ es) {
    __shared__ int cur[RANGE];  // 64 KB
    int c = blockIdx.x / nrange;
    int r = blockIdx.x - c * nrange;
    int r0 = r * RANGE;
    int hi = n - r0; if (hi > RANGE) hi = RANGE;
    for (int i = threadIdx.x; i < hi; i += 1024)
        cur[i] = bases[(size_t)c * n + r0 + i];
    __syncthreads();
    int e0 = (int)((long long)E * c / NCHUNK);
    int e1 = (int)((long long)E * (c + 1) / NCHUNK);
    for (int e = e0 + threadIdx.x * 4; e + 4 <= e1; e += 4096) {
        int4 s4 = *(const int4*)(src + e);
        int4 d4 = *(const int4*)(dst + e);
        int ss[4] = {s4.x, s4.y, s4.z, s4.w};
        int dd[4] = {d4.x, d4.y, d4.z, d4.w};
#pragma unroll
        for (int k = 0; k < 4; ++k) {
            int d = dd[k] - r0;
            if ((unsigned)d < (unsigned)hi) {
                int pos = atomicAdd(&cur[d], 1);
                es[pos] = ss[k];
            }
        }
    }
    int tb = e0 + ((e1 - e0) & ~3);  // scalar tail
    for (int e = tb + threadIdx.x; e < e1; e += 1024) {
        int d = dst[e] - r0;
        if ((unsigned)d < (unsigned)hi) {
            int pos = atomicAdd(&cur[d], 1);
            es[pos] = src[e];
        }
    }
}

// ---------------------------------------------------------------------------
// H1' = dinv * (x @ W1 + b1) stored fp16   (one wave per node)
// ---------------------------------------------------------------------------
__global__ __launch_bounds__(256) void gemm1_kernel(
    const float* __restrict__ x, const float* __restrict__ W1,
    const float* __restrict__ b1, const float* __restrict__ dinv,
    __half* __restrict__ H1h, int n) {
    __shared__ float Wl[NFEAT * NHID];   // 32 KB
    __shared__ float xr[4][NFEAT];
    for (int t = threadIdx.x; t < NFEAT * NHID; t += 256) Wl[t] = W1[t];
    __syncthreads();
    int wave = threadIdx.x >> 6;
    int lane = threadIdx.x & 63;
    float bias = b1[lane];
    int stride = gridDim.x * 4;
    for (int node = blockIdx.x * 4 + wave; node < n; node += stride) {
        xr[wave][lane]      = x[(size_t)node * NFEAT + lane];
        xr[wave][lane + 64] = x[(size_t)node * NFEAT + 64 + lane];
        float acc = bias;
#pragma unroll
        for (int k = 0; k < NFEAT; ++k)
            acc += xr[wave][k] * Wl[k * NHID + lane];
        H1h[(size_t)node * NHID + lane] = __float2half_rn(acc * dinv[node]);
    }
}

// ---------------------------------------------------------------------------
// fused: agg1 (gather-sum of H1' rows) + ReLU + GEMM2 -> H2' fp16
// half2 gathers: 2 rows/step (lanes 0-31 even rows, 32-63 odd rows),
// 8 pairs (16 rows) in flight per unrolled iter; halves merged via shfl_xor.
// ---------------------------------------------------------------------------
__global__ __launch_bounds__(256) void agg1_gemm2_kernel(
    const int* __restrict__ es, const int* __restrict__ row_start,
    const float* __restrict__ dinv, const __half2* __restrict__ H1h2,
    const float* __restrict__ W2, const float* __restrict__ b2,
    __half* __restrict__ H2h, int n) {
    __shared__ float W2l[NHID * NCLASS];  // 10 KB
    __shared__ float rl[4][NHID];
    for (int t = threadIdx.x; t < NHID * NCLASS; t += 256) W2l[t] = W2[t];
    __syncthreads();
    int wave = threadIdx.x >> 6;
    int lane = threadIdx.x & 63;
    int half = lane >> 5;   // 0: even rows, 1: odd rows
    int col = lane & 31;    // half2 column (features 2col, 2col+1)
    float bias2 = (lane < NCLASS) ? b2[lane] : 0.f;
    int stride = gridDim.x * 4;
    for (int node = blockIdx.x * 4 + wave; node < n; node += stride) {
        int e0 = row_start[node], e1 = row_start[node + 1];
        float ax = 0.f, ay = 0.f;
        if (half == 0) {  // self-loop counted once, in the lower half
            __half2 sv = H1h2[(size_t)node * 32 + col];
            ax = __low2float(sv); ay = __high2float(sv);
        }
        for (int e = e0; e < e1; e += 64) {
            int cnt = e1 - e; if (cnt > 64) cnt = 64;
            int myE = es[e + ((lane < cnt) ? lane : 0)];  // one coalesced load
            int j = 0;
            for (; j + 16 <= cnt; j += 16) {
#pragma unroll
                for (int p = 0; p < 8; ++p) {
                    int rr = __shfl(myE, j + 2 * p + half, 64);
                    __half2 v = H1h2[(size_t)rr * 32 + col];
                    ax += __low2float(v); ay += __high2float(v);
                }
            }
            for (; j + 2 <= cnt; j += 2) {
                int rr = __shfl(myE, j + half, 64);
                __half2 v = H1h2[(size_t)rr * 32 + col];
                ax += __low2float(v); ay += __high2float(v);
            }
            if (j < cnt) {  // single leftover row -> lower half only
                int rr = __shfl(myE, j, 64);
                if (half == 0) {
                    __half2 v = H1h2[(size_t)rr * 32 + col];
                    ax += __low2float(v); ay += __high2float(v);
                }
            }
        }
        ax += __shfl_xor(ax, 32, 64);  // merge halves
        ay += __shfl_xor(ay, 32, 64);
        float di = dinv[node];
        if (half == 0) {
            float2 rv = make_float2(fmaxf(ax * di, 0.f), fmaxf(ay * di, 0.f));
            ((float2*)rl[wave])[col] = rv;
        }
        if (lane < NCLASS) {
            float a2 = bias2;
#pragma unroll
            for (int h = 0; h < NHID; ++h)
                a2 += rl[wave][h] * W2l[h * NCLASS + lane];
            H2h[(size_t)node * NCLASS + lane] = __float2half_rn(a2 * di);
        }
    }
}

// ---------------------------------------------------------------------------
// fused: agg2 (gather-sum of H2' rows) + log_softmax -> out
// ---------------------------------------------------------------------------
__global__ __launch_bounds__(256) void agg2_lsm_kernel(
    const int* __restrict__ es, const int* __restrict__ row_start,
    const float* __restrict__ dinv, const __half* __restrict__ H2h,
    float* __restrict__ out, int n) {
    int wave = threadIdx.x >> 6;
    int lane = threadIdx.x & 63;
    bool act = lane < NCLASS;
    int cl = act ? lane : 0;  // safe column for inactive lanes
    int stride = gridDim.x * 4;
    for (int node = blockIdx.x * 4 + wave; node < n; node += stride) {
        int e0 = row_start[node], e1 = row_start[node + 1];
        float acc = __half2float(H2h[(size_t)node * NCLASS + cl]);  // self-loop
        for (int e = e0; e < e1; e += 64) {
            int cnt = e1 - e; if (cnt > 64) cnt = 64;
            int myE = es[e + ((lane < cnt) ? lane : 0)];
            int j = 0;
            for (; j + 8 <= cnt; j += 8) {
                int s0 = __shfl(myE, j, 64), s1 = __shfl(myE, j + 1, 64);
                int s2 = __shfl(myE, j + 2, 64), s3 = __shfl(myE, j + 3, 64);
                int s4 = __shfl(myE, j + 4, 64), s5 = __shfl(myE, j + 5, 64);
                int s6 = __shfl(myE, j + 6, 64), s7 = __shfl(myE, j + 7, 64);
                __half v0 = H2h[(size_t)s0 * NCLASS + cl];
                __half v1 = H2h[(size_t)s1 * NCLASS + cl];
                __half v2 = H2h[(size_t)s2 * NCLASS + cl];
                __half v3 = H2h[(size_t)s3 * NCLASS + cl];
                __half v4 = H2h[(size_t)s4 * NCLASS + cl];
                __half v5 = H2h[(size_t)s5 * NCLASS + cl];
                __half v6 = H2h[(size_t)s6 * NCLASS + cl];
                __half v7 = H2h[(size_t)s7 * NCLASS + cl];
                acc += __half2float(v0) + __half2float(v1) + __half2float(v2) +
                       __half2float(v3) + __half2float(v4) + __half2float(v5) +
                       __half2float(v6) + __half2float(v7);
            }
            for (; j < cnt; ++j) {
                int s = __shfl(myE, j, 64);
                acc += __half2float(H2h[(size_t)s * NCLASS + cl]);
            }
        }
        float val = 0.f, v = -INFINITY;
        if (act) {
            val = acc * dinv[node];
            v = val;
        }
#pragma unroll
        for (int off = 32; off; off >>= 1) v = fmaxf(v, __shfl_xor(v, off, 64));
        float ex = act ? expf(val - v) : 0.f;
#pragma unroll
        for (int off = 32; off; off >>= 1) ex += __shfl_xor(ex, off, 64);
        float lse = logf(ex) + v;
        if (act) out[(size_t)node * NCLASS + lane] = val - lse;
    }
}

// ---------------------------------------------------------------------------
extern "C" void kernel_launch(void* const* d_in, const int* in_sizes, int n_in,
                              void* d_out, int out_size, void* d_ws, size_t ws_size,
                              hipStream_t stream) {
    const float* x  = (const float*)d_in[0];
    const int*   ei = (const int*)d_in[1];
    const float* W1 = (const float*)d_in[2];
    const float* b1 = (const float*)d_in[3];
    const float* W2 = (const float*)d_in[4];
    const float* b2 = (const float*)d_in[5];
    float* out = (float*)d_out;

    const int n = in_sizes[0] / NFEAT;       // 100000
    const int E = in_sizes[1] / 2;           // 1600000
    const int* src = ei;
    const int* dst = ei + E;
    const int nrange = (n + RANGE - 1) / RANGE;  // 7

    // workspace layout (byte offsets). Aliasing (stream-ordered, safe):
    //   es    overlays deg_p  (deg_p dead after reduce_kernel)
    //   H1h   overlays bases  (bases dead after scatter_kernel)
    //   H2h   overlays bases  (same)
    char* ws = (char*)d_ws;
    float*          dinv      = (float*)(ws + 0);                  // 400 KB
    int*            htot      = (int*)(ws + (512 << 10));
    int*            scanned   = (int*)(ws + (1024 << 10));
    int*            row_start = (int*)(ws + (1536 << 10));
    int*            bsums     = (int*)(ws + (2048 << 10));
    unsigned short* deg_p     = (unsigned short*)(ws + (3u << 20));   // 12.8 MB [3,15.8)
    unsigned short* hist_p    = (unsigned short*)(ws + (16u << 20));  // 12.8 MB [16,28.8)
    int*            bases     = (int*)(ws + (29u << 20));             // 25.6 MB [29,54.6)
    int*            es        = (int*)(ws + (3u << 20));              // 6.4 MB  (alias deg_p)
    __half*         H1h       = (__half*)(ws + (29u << 20));          // 12.8 MB (alias bases)
    __half*         H2h       = (__half*)(ws + (42u << 20));          // 8 MB    (alias bases)

    const int blk = 256;
    const int nblk_n = (n + blk - 1) / blk;  // 391
    const int gridbin = NCHUNK * nrange;     // 448

    histdeg_kernel<<<gridbin, 1024, 0, stream>>>(src, dst, E, n, nrange, deg_p, hist_p);
    reduce_kernel<<<nblk_n, blk, 0, stream>>>(deg_p, hist_p, dinv, htot, n);

    scan_block_kernel<<<nblk_n, blk, 0, stream>>>(htot, scanned, bsums, n);
    scan_partials_kernel<<<1, 512, 0, stream>>>(bsums, nblk_n);
    scan_add_kernel<<<nblk_n, blk, 0, stream>>>(scanned, bsums, row_start, n, E);
    base_kernel<<<nblk_n, blk, 0, stream>>>(row_start, hist_p, bases, n);

    scatter_kernel<<<gridbin, 1024, 0, stream>>>(src, dst, E, n, nrange, bases, es);

    gemm1_kernel<<<2048, blk, 0, stream>>>(x, W1, b1, dinv, H1h, n);

    agg1_gemm2_kernel<<<4096, blk, 0, stream>>>(es, row_start, dinv,
                                                (const __half2*)H1h, W2, b2, H2h, n);

    agg2_lsm_kernel<<<4096, blk, 0, stream>>>(es, row_start, dinv, H2h, out, n);
}

// Round 7
// 309.868 us; speedup vs baseline: 1.9574x; 1.1180x over previous
//
#include <hip/hip_runtime.h>
#include <math.h>

#define NFEAT 128
#define NHID 64
#define NCLASS 40
#define NCHUNK 64
#define RANGE 16384   // nodes per LDS range (7 ranges cover 100k)

typedef _Float16 half4_t __attribute__((ext_vector_type(4)));
typedef _Float16 half8_t __attribute__((ext_vector_type(8)));
typedef float f32x4 __attribute__((ext_vector_type(4)));

// ---------------------------------------------------------------------------
// LDS-binned deg(src) + hist(dst), packed 2xu16 counters, no global atomics.
// ---------------------------------------------------------------------------
__global__ __launch_bounds__(1024) void histdeg_kernel(
    const int* __restrict__ src, const int* __restrict__ dst, int E, int n,
    int nrange, unsigned short* __restrict__ deg_p,
    unsigned short* __restrict__ hist_p) {
    __shared__ unsigned int degc[RANGE / 2];   // 32 KB
    __shared__ unsigned int histc[RANGE / 2];  // 32 KB
    int c = blockIdx.x / nrange;
    int r = blockIdx.x - c * nrange;
    int r0 = r * RANGE;
    for (int i = threadIdx.x; i < RANGE / 2; i += 1024) {
        degc[i] = 0u;
        histc[i] = 0u;
    }
    __syncthreads();
    int e0 = (int)((long long)E * c / NCHUNK);
    int e1 = (int)((long long)E * (c + 1) / NCHUNK);
    for (int e = e0 + threadIdx.x * 4; e + 4 <= e1; e += 4096) {
        int4 s4 = *(const int4*)(src + e);
        int4 d4 = *(const int4*)(dst + e);
        int ss[4] = {s4.x, s4.y, s4.z, s4.w};
        int dd[4] = {d4.x, d4.y, d4.z, d4.w};
#pragma unroll
        for (int k = 0; k < 4; ++k) {
            int s = ss[k] - r0, d = dd[k] - r0;
            if ((unsigned)s < (unsigned)RANGE)
                atomicAdd(&degc[s >> 1], 1u << ((s & 1) * 16));
            if ((unsigned)d < (unsigned)RANGE)
                atomicAdd(&histc[d >> 1], 1u << ((d & 1) * 16));
        }
    }
    int tb = e0 + ((e1 - e0) & ~3);  // scalar tail
    for (int e = tb + threadIdx.x; e < e1; e += 1024) {
        int s = src[e] - r0, d = dst[e] - r0;
        if ((unsigned)s < (unsigned)RANGE)
            atomicAdd(&degc[s >> 1], 1u << ((s & 1) * 16));
        if ((unsigned)d < (unsigned)RANGE)
            atomicAdd(&histc[d >> 1], 1u << ((d & 1) * 16));
    }
    __syncthreads();
    int hi = n - r0; if (hi > RANGE) hi = RANGE;
    for (int i = threadIdx.x; i < hi; i += 1024) {
        unsigned dv = (degc[i >> 1] >> ((i & 1) * 16)) & 0xFFFFu;
        unsigned hv = (histc[i >> 1] >> ((i & 1) * 16)) & 0xFFFFu;
        deg_p[(size_t)c * n + r0 + i] = (unsigned short)dv;
        hist_p[(size_t)c * n + r0 + i] = (unsigned short)hv;
    }
}

// deg = 1 + sum_c deg_p ; dinv = rsqrt(deg) ; htot = sum_c hist_p
__global__ void reduce_kernel(const unsigned short* __restrict__ deg_p,
                              const unsigned short* __restrict__ hist_p,
                              float* __restrict__ dinv,
                              int* __restrict__ htot, int n) {
    int i = blockIdx.x * blockDim.x + threadIdx.x;
    if (i >= n) return;
    int d = 1, h = 0;
#pragma unroll 8
    for (int c = 0; c < NCHUNK; ++c) {
        d += deg_p[(size_t)c * n + i];
        h += hist_p[(size_t)c * n + i];
    }
    dinv[i] = rsqrtf((float)d);
    htot[i] = h;
}

// ---------------------------------------------------------------------------
// exclusive scan of htot[n] -> row_start[n+1]  (3 kernels)
// ---------------------------------------------------------------------------
__global__ void scan_block_kernel(const int* __restrict__ hist,
                                  int* __restrict__ scanned,
                                  int* __restrict__ bsums, int n) {
    __shared__ int tmp[256];
    int i = blockIdx.x * 256 + threadIdx.x;
    int v = (i < n) ? hist[i] : 0;
    tmp[threadIdx.x] = v;
    __syncthreads();
#pragma unroll
    for (int off = 1; off < 256; off <<= 1) {
        int t = (threadIdx.x >= off) ? tmp[threadIdx.x - off] : 0;
        __syncthreads();
        tmp[threadIdx.x] += t;
        __syncthreads();
    }
    if (i < n) scanned[i] = tmp[threadIdx.x] - v;  // exclusive
    if (threadIdx.x == 255) bsums[blockIdx.x] = tmp[255];
}

__global__ void scan_partials_kernel(int* __restrict__ bsums, int nb) {
    __shared__ int tmp[512];
    int v = (threadIdx.x < nb) ? bsums[threadIdx.x] : 0;
    tmp[threadIdx.x] = v;
    __syncthreads();
#pragma unroll
    for (int off = 1; off < 512; off <<= 1) {
        int t = (threadIdx.x >= off) ? tmp[threadIdx.x - off] : 0;
        __syncthreads();
        tmp[threadIdx.x] += t;
        __syncthreads();
    }
    if (threadIdx.x < nb) bsums[threadIdx.x] = tmp[threadIdx.x] - v;  // exclusive
}

__global__ void scan_add_kernel(const int* __restrict__ scanned,
                                const int* __restrict__ bsums,
                                int* __restrict__ row_start, int n, int E) {
    int i = blockIdx.x * 256 + threadIdx.x;
    if (i < n) row_start[i] = scanned[i] + bsums[blockIdx.x];
    if (i == 0) row_start[n] = E;
}

// per-chunk cursor bases: bases[c][i] = row_start[i] + sum_{t<c} hist_p[t][i]
__global__ void base_kernel(const int* __restrict__ row_start,
                            const unsigned short* __restrict__ hist_p,
                            int* __restrict__ bases, int n) {
    int i = blockIdx.x * blockDim.x + threadIdx.x;
    if (i >= n) return;
    int r = row_start[i];
#pragma unroll 8
    for (int c = 0; c < NCHUNK; ++c) {
        bases[(size_t)c * n + i] = r;
        r += hist_p[(size_t)c * n + i];
    }
}

// ---------------------------------------------------------------------------
// scatter: counting-sort edge srcs by dst; cursors in LDS; int4 edge loads.
// ---------------------------------------------------------------------------
__global__ __launch_bounds__(1024) void scatter_kernel(
    const int* __restrict__ src, const int* __restrict__ dst, int E, int n,
    int nrange, const int* __restrict__ bases, int* __restrict__ es) {
    __shared__ int cur[RANGE];  // 64 KB
    int c = blockIdx.x / nrange;
    int r = blockIdx.x - c * nrange;
    int r0 = r * RANGE;
    int hi = n - r0; if (hi > RANGE) hi = RANGE;
    for (int i = threadIdx.x; i < hi; i += 1024)
        cur[i] = bases[(size_t)c * n + r0 + i];
    __syncthreads();
    int e0 = (int)((long long)E * c / NCHUNK);
    int e1 = (int)((long long)E * (c + 1) / NCHUNK);
    for (int e = e0 + threadIdx.x * 4; e + 4 <= e1; e += 4096) {
        int4 s4 = *(const int4*)(src + e);
        int4 d4 = *(const int4*)(dst + e);
        int ss[4] = {s4.x, s4.y, s4.z, s4.w};
        int dd[4] = {d4.x, d4.y, d4.z, d4.w};
#pragma unroll
        for (int k = 0; k < 4; ++k) {
            int d = dd[k] - r0;
            if ((unsigned)d < (unsigned)hi) {
                int pos = atomicAdd(&cur[d], 1);
                es[pos] = ss[k];
            }
        }
    }
    int tb = e0 + ((e1 - e0) & ~3);  // scalar tail
    for (int e = tb + threadIdx.x; e < e1; e += 1024) {
        int d = dst[e] - r0;
        if ((unsigned)d < (unsigned)hi) {
            int pos = atomicAdd(&cur[d], 1);
            es[pos] = src[e];
        }
    }
}

// ---------------------------------------------------------------------------
// gemm1 (MFMA): H1' = dinv * (x @ W1 + b1), fp16 out.
// Per wave: one 16-row M-tile, N=64 as 4 N-tiles, K=128 as 4 K-steps.
// W1 fragments live in registers (loaded once per thread).
// Fragment layout (guide §3, m89-verified): A row=lane&15, k=(lane>>4)*8+j;
// B col=lane&15, same k; D col=lane&15, row=(lane>>4)*4+reg.
// ---------------------------------------------------------------------------
__global__ __launch_bounds__(256) void gemm1_mfma_kernel(
    const float* __restrict__ x, const float* __restrict__ W1,
    const float* __restrict__ b1, const float* __restrict__ dinv,
    _Float16* __restrict__ H1, int n) {
    int wave = threadIdx.x >> 6;
    int lane = threadIdx.x & 63;
    int lr = lane & 15;
    int kg = lane >> 4;
    // B fragments: [kstep][ntile]
    half8_t bf[4][4];
    float b1v[4];
#pragma unroll
    for (int t = 0; t < 4; ++t) {
        int col = t * 16 + lr;
        b1v[t] = b1[col];
#pragma unroll
        for (int ks = 0; ks < 4; ++ks) {
            int kb = ks * 32 + kg * 8;
            half8_t hb;
#pragma unroll
            for (int j = 0; j < 8; ++j) hb[j] = (_Float16)W1[(kb + j) * NHID + col];
            bf[ks][t] = hb;
        }
    }
    int nt16 = (n + 15) >> 4;
    for (int gt = blockIdx.x * 4 + wave; gt < nt16; gt += gridDim.x * 4) {
        int m0 = gt * 16;
        int arow = m0 + lr; if (arow >= n) arow = n - 1;
        f32x4 acc[4] = {f32x4{0,0,0,0}, f32x4{0,0,0,0}, f32x4{0,0,0,0}, f32x4{0,0,0,0}};
#pragma unroll
        for (int ks = 0; ks < 4; ++ks) {
            const float* ap = x + (size_t)arow * NFEAT + ks * 32 + kg * 8;
            float4 a0 = *(const float4*)ap;
            float4 a1 = *(const float4*)(ap + 4);
            half8_t af;
            af[0] = (_Float16)a0.x; af[1] = (_Float16)a0.y;
            af[2] = (_Float16)a0.z; af[3] = (_Float16)a0.w;
            af[4] = (_Float16)a1.x; af[5] = (_Float16)a1.y;
            af[6] = (_Float16)a1.z; af[7] = (_Float16)a1.w;
#pragma unroll
            for (int t = 0; t < 4; ++t)
                acc[t] = __builtin_amdgcn_mfma_f32_16x16x32_f16(af, bf[ks][t], acc[t], 0, 0, 0);
        }
        int r0 = m0 + kg * 4;
        float dv[4];
#pragma unroll
        for (int r = 0; r < 4; ++r) {
            int rr = r0 + r;
            dv[r] = (rr < n) ? dinv[rr] : 0.f;
        }
#pragma unroll
        for (int t = 0; t < 4; ++t)
#pragma unroll
            for (int r = 0; r < 4; ++r) {
                int rr = r0 + r;
                if (rr < n)
                    H1[(size_t)rr * NHID + t * 16 + lr] =
                        (_Float16)((acc[t][r] + b1v[t]) * dv[r]);
            }
    }
}

// ---------------------------------------------------------------------------
// agg1: AGG[d] = relu(dinv[d] * (H1'[d] + sum_{s in N(d)} H1'[s])), fp16.
// lane = 16q+m: 4 edges per gather pass, each 16-lane group loads one row
// as half4 (8B). Merge halves via shfl_xor(16|32).
// ---------------------------------------------------------------------------
__global__ __launch_bounds__(256) void agg1_kernel(
    const int* __restrict__ es, const int* __restrict__ row_start,
    const float* __restrict__ dinv, const _Float16* __restrict__ H1,
    _Float16* __restrict__ AGG, int n) {
    int wave = threadIdx.x >> 6;
    int lane = threadIdx.x & 63;
    int q = lane >> 4;   // edge slot within pass
    int m = lane & 15;   // feature quad
    int stride = gridDim.x * 4;
    for (int node = blockIdx.x * 4 + wave; node < n; node += stride) {
        int e0 = row_start[node], e1 = row_start[node + 1];
        float a0 = 0.f, a1 = 0.f, a2 = 0.f, a3 = 0.f;
        for (int e = e0; e < e1; e += 64) {
            int cnt = e1 - e; if (cnt > 64) cnt = 64;
            int myE = es[e + ((lane < cnt) ? lane : 0)];
            for (int j = 0; j < cnt; j += 16) {
#pragma unroll
                for (int p = 0; p < 4; ++p) {
                    int jj = j + 4 * p + q;
                    int rr = __shfl(myE, jj, 64);
                    if (jj < cnt) {
                        half4_t v = *(const half4_t*)(H1 + (size_t)rr * NHID + 4 * m);
                        a0 += (float)v[0]; a1 += (float)v[1];
                        a2 += (float)v[2]; a3 += (float)v[3];
                    }
                }
            }
        }
        if (q == 0) {  // self-loop, counted once
            half4_t v = *(const half4_t*)(H1 + (size_t)node * NHID + 4 * m);
            a0 += (float)v[0]; a1 += (float)v[1];
            a2 += (float)v[2]; a3 += (float)v[3];
        }
        a0 += __shfl_xor(a0, 16, 64); a0 += __shfl_xor(a0, 32, 64);
        a1 += __shfl_xor(a1, 16, 64); a1 += __shfl_xor(a1, 32, 64);
        a2 += __shfl_xor(a2, 16, 64); a2 += __shfl_xor(a2, 32, 64);
        a3 += __shfl_xor(a3, 16, 64); a3 += __shfl_xor(a3, 32, 64);
        float di = dinv[node];
        if (lane < 16) {
            half4_t o;
            o[0] = (_Float16)fmaxf(a0 * di, 0.f);
            o[1] = (_Float16)fmaxf(a1 * di, 0.f);
            o[2] = (_Float16)fmaxf(a2 * di, 0.f);
            o[3] = (_Float16)fmaxf(a3 * di, 0.f);
            *(half4_t*)(AGG + (size_t)node * NHID + 4 * lane) = o;
        }
    }
}

// ---------------------------------------------------------------------------
// gemm2 (MFMA): H2' = dinv * (AGG @ W2 + b2), fp16, rows padded to 64 cols
// (cols >= 40 zero/ignored). K=64 (2 K-steps), N=40 -> 3 N-tiles (48, masked).
// ---------------------------------------------------------------------------
__global__ __launch_bounds__(256) void gemm2_mfma_kernel(
    const _Float16* __restrict__ AGG, const float* __restrict__ W2,
    const float* __restrict__ b2, const float* __restrict__ dinv,
    _Float16* __restrict__ H2, int n) {
    int wave = threadIdx.x >> 6;
    int lane = threadIdx.x & 63;
    int lr = lane & 15;
    int kg = lane >> 4;
    half8_t bf[2][3];
    float b2v[3];
#pragma unroll
    for (int t = 0; t < 3; ++t) {
        int col = t * 16 + lr;
        b2v[t] = (col < NCLASS) ? b2[col] : 0.f;
#pragma unroll
        for (int ks = 0; ks < 2; ++ks) {
            int kb = ks * 32 + kg * 8;
            half8_t hb;
#pragma unroll
            for (int j = 0; j < 8; ++j)
                hb[j] = (col < NCLASS) ? (_Float16)W2[(kb + j) * NCLASS + col]
                                       : (_Float16)0.f;
            bf[ks][t] = hb;
        }
    }
    int nt16 = (n + 15) >> 4;
    for (int gt = blockIdx.x * 4 + wave; gt < nt16; gt += gridDim.x * 4) {
        int m0 = gt * 16;
        int arow = m0 + lr; if (arow >= n) arow = n - 1;
        f32x4 acc[3] = {f32x4{0,0,0,0}, f32x4{0,0,0,0}, f32x4{0,0,0,0}};
#pragma unroll
        for (int ks = 0; ks < 2; ++ks) {
            half8_t af = *(const half8_t*)(AGG + (size_t)arow * NHID + ks * 32 + kg * 8);
#pragma unroll
            for (int t = 0; t < 3; ++t)
                acc[t] = __builtin_amdgcn_mfma_f32_16x16x32_f16(af, bf[ks][t], acc[t], 0, 0, 0);
        }
        int r0 = m0 + kg * 4;
        float dv[4];
#pragma unroll
        for (int r = 0; r < 4; ++r) {
            int rr = r0 + r;
            dv[r] = (rr < n) ? dinv[rr] : 0.f;
        }
#pragma unroll
        for (int t = 0; t < 3; ++t) {
            int col = t * 16 + lr;
#pragma unroll
            for (int r = 0; r < 4; ++r) {
                int rr = r0 + r;
                if (rr < n)
                    H2[(size_t)rr * 64 + col] =
                        (col < NCLASS) ? (_Float16)((acc[t][r] + b2v[t]) * dv[r])
                                       : (_Float16)0.f;
            }
        }
    }
}

// ---------------------------------------------------------------------------
// agg2 + log_softmax -> out. Same quad-gather structure over 64-padded H2'
// rows; features >= 40 isolated in lanes m >= 10 and masked out of the lsm.
// ---------------------------------------------------------------------------
__global__ __launch_bounds__(256) void agg2_lsm_kernel(
    const int* __restrict__ es, const int* __restrict__ row_start,
    const float* __restrict__ dinv, const _Float16* __restrict__ H2,
    float* __restrict__ out, int n) {
    int wave = threadIdx.x >> 6;
    int lane = threadIdx.x & 63;
    int q = lane >> 4;
    int m = lane & 15;
    int stride = gridDim.x * 4;
    for (int node = blockIdx.x * 4 + wave; node < n; node += stride) {
        int e0 = row_start[node], e1 = row_start[node + 1];
        float a0 = 0.f, a1 = 0.f, a2 = 0.f, a3 = 0.f;
        for (int e = e0; e < e1; e += 64) {
            int cnt = e1 - e; if (cnt > 64) cnt = 64;
            int myE = es[e + ((lane < cnt) ? lane : 0)];
            for (int j = 0; j < cnt; j += 16) {
#pragma unroll
                for (int p = 0; p < 4; ++p) {
                    int jj = j + 4 * p + q;
                    int rr = __shfl(myE, jj, 64);
                    if (jj < cnt) {
                        half4_t v = *(const half4_t*)(H2 + (size_t)rr * 64 + 4 * m);
                        a0 += (float)v[0]; a1 += (float)v[1];
                        a2 += (float)v[2]; a3 += (float)v[3];
                    }
                }
            }
        }
        if (q == 0) {  // self-loop
            half4_t v = *(const half4_t*)(H2 + (size_t)node * 64 + 4 * m);
            a0 += (float)v[0]; a1 += (float)v[1];
            a2 += (float)v[2]; a3 += (float)v[3];
        }
        a0 += __shfl_xor(a0, 16, 64); a0 += __shfl_xor(a0, 32, 64);
        a1 += __shfl_xor(a1, 16, 64); a1 += __shfl_xor(a1, 32, 64);
        a2 += __shfl_xor(a2, 16, 64); a2 += __shfl_xor(a2, 32, 64);
        a3 += __shfl_xor(a3, 16, 64); a3 += __shfl_xor(a3, 32, 64);
        float di = dinv[node];
        float v0 = a0 * di, v1 = a1 * di, v2 = a2 * di, v3 = a3 * di;
        bool valid = (m < 10);  // features 4m..4m+3 < 40
        float vmax = valid ? fmaxf(fmaxf(v0, v1), fmaxf(v2, v3)) : -INFINITY;
#pragma unroll
        for (int off = 8; off; off >>= 1) vmax = fmaxf(vmax, __shfl_xor(vmax, off, 64));
        float sume = valid ? (__expf(v0 - vmax) + __expf(v1 - vmax) +
                              __expf(v2 - vmax) + __expf(v3 - vmax)) : 0.f;
#pragma unroll
        for (int off = 8; off; off >>= 1) sume += __shfl_xor(sume, off, 64);
        float lse = __logf(sume) + vmax;
        if (lane < 10) {
            float4 o = make_float4(v0 - lse, v1 - lse, v2 - lse, v3 - lse);
            *(float4*)(out + (size_t)node * NCLASS + 4 * lane) = o;
        }
    }
}

// ---------------------------------------------------------------------------
extern "C" void kernel_launch(void* const* d_in, const int* in_sizes, int n_in,
                              void* d_out, int out_size, void* d_ws, size_t ws_size,
                              hipStream_t stream) {
    const float* x  = (const float*)d_in[0];
    const int*   ei = (const int*)d_in[1];
    const float* W1 = (const float*)d_in[2];
    const float* b1 = (const float*)d_in[3];
    const float* W2 = (const float*)d_in[4];
    const float* b2 = (const float*)d_in[5];
    float* out = (float*)d_out;

    const int n = in_sizes[0] / NFEAT;       // 100000
    const int E = in_sizes[1] / 2;           // 1600000
    const int* src = ei;
    const int* dst = ei + E;
    const int nrange = (n + RANGE - 1) / RANGE;  // 7

    // workspace layout. Aliasing (stream-ordered, safe):
    //   es   over deg_p  (deg_p dead after reduce)
    //   H2   over hist_p (hist_p dead after base)
    //   H1/AGG over bases (bases dead after scatter)
    char* ws = (char*)d_ws;
    float*          dinv      = (float*)(ws + 0);                     // 400 KB
    int*            htot      = (int*)(ws + (512 << 10));
    int*            scanned   = (int*)(ws + (1024 << 10));
    int*            row_start = (int*)(ws + (1536 << 10));
    int*            bsums     = (int*)(ws + (2048 << 10));
    unsigned short* deg_p     = (unsigned short*)(ws + (3u << 20));   // 12.8 MB [3,15.8)
    unsigned short* hist_p    = (unsigned short*)(ws + (16u << 20));  // 12.8 MB [16,28.8)
    int*            bases     = (int*)(ws + (29u << 20));             // 25.6 MB [29,54.6)
    int*            es        = (int*)(ws + (3u << 20));              // 6.4 MB  (alias deg_p)
    _Float16*       H2        = (_Float16*)(ws + (16u << 20));        // 12.8 MB (alias hist_p)
    _Float16*       H1        = (_Float16*)(ws + (29u << 20));        // 12.8 MB (alias bases)
    _Float16*       AGG       = (_Float16*)(ws + (42u << 20));        // 12.8 MB (alias bases)

    const int blk = 256;
    const int nblk_n = (n + blk - 1) / blk;  // 391
    const int gridbin = NCHUNK * nrange;     // 448

    histdeg_kernel<<<gridbin, 1024, 0, stream>>>(src, dst, E, n, nrange, deg_p, hist_p);
    reduce_kernel<<<nblk_n, blk, 0, stream>>>(deg_p, hist_p, dinv, htot, n);

    scan_block_kernel<<<nblk_n, blk, 0, stream>>>(htot, scanned, bsums, n);
    scan_partials_kernel<<<1, 512, 0, stream>>>(bsums, nblk_n);
    scan_add_kernel<<<nblk_n, blk, 0, stream>>>(scanned, bsums, row_start, n, E);
    base_kernel<<<nblk_n, blk, 0, stream>>>(row_start, hist_p, bases, n);

    scatter_kernel<<<gridbin, 1024, 0, stream>>>(src, dst, E, n, nrange, bases, es);

    gemm1_mfma_kernel<<<512, blk, 0, stream>>>(x, W1, b1, dinv, H1, n);

    agg1_kernel<<<4096, blk, 0, stream>>>(es, row_start, dinv, H1, AGG, n);

    gemm2_mfma_kernel<<<512, blk, 0, stream>>>(AGG, W2, b2, dinv, H2, n);

    agg2_lsm_kernel<<<4096, blk, 0, stream>>>(es, row_start, dinv, H2, out, n);
}

// Round 8
// 306.377 us; speedup vs baseline: 1.9797x; 1.0114x over previous
//
#include <hip/hip_runtime.h>
#include <math.h>

#define NFEAT 128
#define NHID 64
#define NCLASS 40
#define NCHUNK 64
#define RANGE_H 32768 // histdeg LDS range (128 KiB LDS, 4 ranges cover 100k)
#define RANGE_S 16384 // scatter LDS range (64 KiB cursors, 7 ranges)

typedef _Float16 half4_t __attribute__((ext_vector_type(4)));
typedef _Float16 half8_t __attribute__((ext_vector_type(8)));
typedef float f32x4 __attribute__((ext_vector_type(4)));

// ---------------------------------------------------------------------------
// LDS-binned deg(src) + hist(dst), packed 2xu16 counters, no global atomics.
// 128 KiB LDS -> RANGE_H=32768, only 4 edge passes. 1 block/CU.
// ---------------------------------------------------------------------------
__global__ __launch_bounds__(1024) void histdeg_kernel(
    const int* __restrict__ src, const int* __restrict__ dst, int E, int n,
    int nrange, unsigned short* __restrict__ deg_p,
    unsigned short* __restrict__ hist_p) {
    __shared__ unsigned int degc[RANGE_H / 2];   // 64 KB
    __shared__ unsigned int histc[RANGE_H / 2];  // 64 KB
    int c = blockIdx.x / nrange;
    int r = blockIdx.x - c * nrange;
    int r0 = r * RANGE_H;
    for (int i = threadIdx.x; i < RANGE_H / 2; i += 1024) {
        degc[i] = 0u;
        histc[i] = 0u;
    }
    __syncthreads();
    int e0 = (int)((long long)E * c / NCHUNK);
    int e1 = (int)((long long)E * (c + 1) / NCHUNK);
    for (int e = e0 + threadIdx.x * 4; e + 4 <= e1; e += 4096) {
        int4 s4 = *(const int4*)(src + e);
        int4 d4 = *(const int4*)(dst + e);
        int ss[4] = {s4.x, s4.y, s4.z, s4.w};
        int dd[4] = {d4.x, d4.y, d4.z, d4.w};
#pragma unroll
        for (int k = 0; k < 4; ++k) {
            int s = ss[k] - r0, d = dd[k] - r0;
            if ((unsigned)s < (unsigned)RANGE_H)
                atomicAdd(&degc[s >> 1], 1u << ((s & 1) * 16));
            if ((unsigned)d < (unsigned)RANGE_H)
                atomicAdd(&histc[d >> 1], 1u << ((d & 1) * 16));
        }
    }
    int tb = e0 + ((e1 - e0) & ~3);  // scalar tail
    for (int e = tb + threadIdx.x; e < e1; e += 1024) {
        int s = src[e] - r0, d = dst[e] - r0;
        if ((unsigned)s < (unsigned)RANGE_H)
            atomicAdd(&degc[s >> 1], 1u << ((s & 1) * 16));
        if ((unsigned)d < (unsigned)RANGE_H)
            atomicAdd(&histc[d >> 1], 1u << ((d & 1) * 16));
    }
    __syncthreads();
    int hi = n - r0; if (hi > RANGE_H) hi = RANGE_H;
    for (int i = threadIdx.x; i < hi; i += 1024) {
        unsigned dv = (degc[i >> 1] >> ((i & 1) * 16)) & 0xFFFFu;
        unsigned hv = (histc[i >> 1] >> ((i & 1) * 16)) & 0xFFFFu;
        deg_p[(size_t)c * n + r0 + i] = (unsigned short)dv;
        hist_p[(size_t)c * n + r0 + i] = (unsigned short)hv;
    }
}

// deg = 1 + sum_c deg_p ; dinv = rsqrt(deg) ; htot = sum_c hist_p
__global__ void reduce_kernel(const unsigned short* __restrict__ deg_p,
                              const unsigned short* __restrict__ hist_p,
                              float* __restrict__ dinv,
                              int* __restrict__ htot, int n) {
    int i = blockIdx.x * blockDim.x + threadIdx.x;
    if (i >= n) return;
    int d = 1, h = 0;
#pragma unroll 8
    for (int c = 0; c < NCHUNK; ++c) {
        d += deg_p[(size_t)c * n + i];
        h += hist_p[(size_t)c * n + i];
    }
    dinv[i] = rsqrtf((float)d);
    htot[i] = h;
}

// ---------------------------------------------------------------------------
// exclusive scan of htot[n] -> row_start[n+1]  (3 kernels)
// ---------------------------------------------------------------------------
__global__ void scan_block_kernel(const int* __restrict__ hist,
                                  int* __restrict__ scanned,
                                  int* __restrict__ bsums, int n) {
    __shared__ int tmp[256];
    int i = blockIdx.x * 256 + threadIdx.x;
    int v = (i < n) ? hist[i] : 0;
    tmp[threadIdx.x] = v;
    __syncthreads();
#pragma unroll
    for (int off = 1; off < 256; off <<= 1) {
        int t = (threadIdx.x >= off) ? tmp[threadIdx.x - off] : 0;
        __syncthreads();
        tmp[threadIdx.x] += t;
        __syncthreads();
    }
    if (i < n) scanned[i] = tmp[threadIdx.x] - v;  // exclusive
    if (threadIdx.x == 255) bsums[blockIdx.x] = tmp[255];
}

__global__ void scan_partials_kernel(int* __restrict__ bsums, int nb) {
    __shared__ int tmp[512];
    int v = (threadIdx.x < nb) ? bsums[threadIdx.x] : 0;
    tmp[threadIdx.x] = v;
    __syncthreads();
#pragma unroll
    for (int off = 1; off < 512; off <<= 1) {
        int t = (threadIdx.x >= off) ? tmp[threadIdx.x - off] : 0;
        __syncthreads();
        tmp[threadIdx.x] += t;
        __syncthreads();
    }
    if (threadIdx.x < nb) bsums[threadIdx.x] = tmp[threadIdx.x] - v;  // exclusive
}

__global__ void scan_add_kernel(const int* __restrict__ scanned,
                                const int* __restrict__ bsums,
                                int* __restrict__ row_start, int n, int E) {
    int i = blockIdx.x * 256 + threadIdx.x;
    if (i < n) row_start[i] = scanned[i] + bsums[blockIdx.x];
    if (i == 0) row_start[n] = E;
}

// per-chunk cursor bases: bases[c][i] = row_start[i] + sum_{t<c} hist_p[t][i]
__global__ void base_kernel(const int* __restrict__ row_start,
                            const unsigned short* __restrict__ hist_p,
                            int* __restrict__ bases, int n) {
    int i = blockIdx.x * blockDim.x + threadIdx.x;
    if (i >= n) return;
    int r = row_start[i];
#pragma unroll 8
    for (int c = 0; c < NCHUNK; ++c) {
        bases[(size_t)c * n + i] = r;
        r += hist_p[(size_t)c * n + i];
    }
}

// ---------------------------------------------------------------------------
// scatter: counting-sort edge srcs by dst; cursors in LDS; int4 edge loads.
// ---------------------------------------------------------------------------
__global__ __launch_bounds__(1024) void scatter_kernel(
    const int* __restrict__ src, const int* __restrict__ dst, int E, int n,
    int nrange, const int* __restrict__ bases, int* __restrict__ es) {
    __shared__ int cur[RANGE_S];  // 64 KB
    int c = blockIdx.x / nrange;
    int r = blockIdx.x - c * nrange;
    int r0 = r * RANGE_S;
    int hi = n - r0; if (hi > RANGE_S) hi = RANGE_S;
    for (int i = threadIdx.x; i < hi; i += 1024)
        cur[i] = bases[(size_t)c * n + r0 + i];
    __syncthreads();
    int e0 = (int)((long long)E * c / NCHUNK);
    int e1 = (int)((long long)E * (c + 1) / NCHUNK);
    for (int e = e0 + threadIdx.x * 4; e + 4 <= e1; e += 4096) {
        int4 s4 = *(const int4*)(src + e);
        int4 d4 = *(const int4*)(dst + e);
        int ss[4] = {s4.x, s4.y, s4.z, s4.w};
        int dd[4] = {d4.x, d4.y, d4.z, d4.w};
#pragma unroll
        for (int k = 0; k < 4; ++k) {
            int d = dd[k] - r0;
            if ((unsigned)d < (unsigned)hi) {
                int pos = atomicAdd(&cur[d], 1);
                es[pos] = ss[k];
            }
        }
    }
    int tb = e0 + ((e1 - e0) & ~3);  // scalar tail
    for (int e = tb + threadIdx.x; e < e1; e += 1024) {
        int d = dst[e] - r0;
        if ((unsigned)d < (unsigned)hi) {
            int pos = atomicAdd(&cur[d], 1);
            es[pos] = src[e];
        }
    }
}

// ---------------------------------------------------------------------------
// gemm1 (MFMA): H1' = dinv * (x @ W1 + b1), fp16 out, stride 64.
// ---------------------------------------------------------------------------
__global__ __launch_bounds__(256) void gemm1_mfma_kernel(
    const float* __restrict__ x, const float* __restrict__ W1,
    const float* __restrict__ b1, const float* __restrict__ dinv,
    _Float16* __restrict__ H1, int n) {
    int wave = threadIdx.x >> 6;
    int lane = threadIdx.x & 63;
    int lr = lane & 15;
    int kg = lane >> 4;
    half8_t bf[4][4];
    float b1v[4];
#pragma unroll
    for (int t = 0; t < 4; ++t) {
        int col = t * 16 + lr;
        b1v[t] = b1[col];
#pragma unroll
        for (int ks = 0; ks < 4; ++ks) {
            int kb = ks * 32 + kg * 8;
            half8_t hb;
#pragma unroll
            for (int j = 0; j < 8; ++j) hb[j] = (_Float16)W1[(kb + j) * NHID + col];
            bf[ks][t] = hb;
        }
    }
    int nt16 = (n + 15) >> 4;
    for (int gt = blockIdx.x * 4 + wave; gt < nt16; gt += gridDim.x * 4) {
        int m0 = gt * 16;
        int arow = m0 + lr; if (arow >= n) arow = n - 1;
        f32x4 acc[4] = {f32x4{0,0,0,0}, f32x4{0,0,0,0}, f32x4{0,0,0,0}, f32x4{0,0,0,0}};
#pragma unroll
        for (int ks = 0; ks < 4; ++ks) {
            const float* ap = x + (size_t)arow * NFEAT + ks * 32 + kg * 8;
            float4 a0 = *(const float4*)ap;
            float4 a1 = *(const float4*)(ap + 4);
            half8_t af;
            af[0] = (_Float16)a0.x; af[1] = (_Float16)a0.y;
            af[2] = (_Float16)a0.z; af[3] = (_Float16)a0.w;
            af[4] = (_Float16)a1.x; af[5] = (_Float16)a1.y;
            af[6] = (_Float16)a1.z; af[7] = (_Float16)a1.w;
#pragma unroll
            for (int t = 0; t < 4; ++t)
                acc[t] = __builtin_amdgcn_mfma_f32_16x16x32_f16(af, bf[ks][t], acc[t], 0, 0, 0);
        }
        int r0 = m0 + kg * 4;
        float dv[4];
#pragma unroll
        for (int r = 0; r < 4; ++r) {
            int rr = r0 + r;
            dv[r] = (rr < n) ? dinv[rr] : 0.f;
        }
#pragma unroll
        for (int t = 0; t < 4; ++t)
#pragma unroll
            for (int r = 0; r < 4; ++r) {
                int rr = r0 + r;
                if (rr < n)
                    H1[(size_t)rr * NHID + t * 16 + lr] =
                        (_Float16)((acc[t][r] + b1v[t]) * dv[r]);
            }
    }
}

// ---------------------------------------------------------------------------
// agg1: AGG[d] = relu(dinv[d] * (H1'[d] + sum_{s in N(d)} H1'[s])), fp16.
// lane = 16q+m: 4 edges per pass, 16-lane groups load half4 rows.
// ---------------------------------------------------------------------------
__global__ __launch_bounds__(256) void agg1_kernel(
    const int* __restrict__ es, const int* __restrict__ row_start,
    const float* __restrict__ dinv, const _Float16* __restrict__ H1,
    _Float16* __restrict__ AGG, int n) {
    int wave = threadIdx.x >> 6;
    int lane = threadIdx.x & 63;
    int q = lane >> 4;
    int m = lane & 15;
    int stride = gridDim.x * 4;
    for (int node = blockIdx.x * 4 + wave; node < n; node += stride) {
        int e0 = row_start[node], e1 = row_start[node + 1];
        float a0 = 0.f, a1 = 0.f, a2 = 0.f, a3 = 0.f;
        for (int e = e0; e < e1; e += 64) {
            int cnt = e1 - e; if (cnt > 64) cnt = 64;
            int myE = es[e + ((lane < cnt) ? lane : 0)];
            for (int j = 0; j < cnt; j += 16) {
#pragma unroll
                for (int p = 0; p < 4; ++p) {
                    int jj = j + 4 * p + q;
                    int rr = __shfl(myE, jj, 64);
                    if (jj < cnt) {
                        int off = (rr << 6) + (m << 2);  // 32-bit halves offset
                        half4_t v = *(const half4_t*)(H1 + off);
                        a0 += (float)v[0]; a1 += (float)v[1];
                        a2 += (float)v[2]; a3 += (float)v[3];
                    }
                }
            }
        }
        if (q == 0) {  // self-loop, counted once
            half4_t v = *(const half4_t*)(H1 + (node << 6) + (m << 2));
            a0 += (float)v[0]; a1 += (float)v[1];
            a2 += (float)v[2]; a3 += (float)v[3];
        }
        a0 += __shfl_xor(a0, 16, 64); a0 += __shfl_xor(a0, 32, 64);
        a1 += __shfl_xor(a1, 16, 64); a1 += __shfl_xor(a1, 32, 64);
        a2 += __shfl_xor(a2, 16, 64); a2 += __shfl_xor(a2, 32, 64);
        a3 += __shfl_xor(a3, 16, 64); a3 += __shfl_xor(a3, 32, 64);
        float di = dinv[node];
        if (lane < 16) {
            half4_t o;
            o[0] = (_Float16)fmaxf(a0 * di, 0.f);
            o[1] = (_Float16)fmaxf(a1 * di, 0.f);
            o[2] = (_Float16)fmaxf(a2 * di, 0.f);
            o[3] = (_Float16)fmaxf(a3 * di, 0.f);
            *(half4_t*)(AGG + (node << 6) + (lane << 2)) = o;
        }
    }
}

// ---------------------------------------------------------------------------
// gemm2 (MFMA): H2' = dinv * (AGG @ W2 + b2), fp16, COMPACT 40-col rows.
// K=64 (2 K-steps), N=40 -> tiles t=0,1 full, t=2 stores lr<8 only.
// ---------------------------------------------------------------------------
__global__ __launch_bounds__(256) void gemm2_mfma_kernel(
    const _Float16* __restrict__ AGG, const float* __restrict__ W2,
    const float* __restrict__ b2, const float* __restrict__ dinv,
    _Float16* __restrict__ H2, int n) {
    int wave = threadIdx.x >> 6;
    int lane = threadIdx.x & 63;
    int lr = lane & 15;
    int kg = lane >> 4;
    half8_t bf[2][3];
    float b2v[3];
#pragma unroll
    for (int t = 0; t < 3; ++t) {
        int col = t * 16 + lr;
        b2v[t] = (col < NCLASS) ? b2[col] : 0.f;
#pragma unroll
        for (int ks = 0; ks < 2; ++ks) {
            int kb = ks * 32 + kg * 8;
            half8_t hb;
#pragma unroll
            for (int j = 0; j < 8; ++j)
                hb[j] = (col < NCLASS) ? (_Float16)W2[(kb + j) * NCLASS + col]
                                       : (_Float16)0.f;
            bf[ks][t] = hb;
        }
    }
    int nt16 = (n + 15) >> 4;
    for (int gt = blockIdx.x * 4 + wave; gt < nt16; gt += gridDim.x * 4) {
        int m0 = gt * 16;
        int arow = m0 + lr; if (arow >= n) arow = n - 1;
        f32x4 acc[3] = {f32x4{0,0,0,0}, f32x4{0,0,0,0}, f32x4{0,0,0,0}};
#pragma unroll
        for (int ks = 0; ks < 2; ++ks) {
            half8_t af = *(const half8_t*)(AGG + ((size_t)arow << 6) + ks * 32 + kg * 8);
#pragma unroll
            for (int t = 0; t < 3; ++t)
                acc[t] = __builtin_amdgcn_mfma_f32_16x16x32_f16(af, bf[ks][t], acc[t], 0, 0, 0);
        }
        int r0 = m0 + kg * 4;
        float dv[4];
#pragma unroll
        for (int r = 0; r < 4; ++r) {
            int rr = r0 + r;
            dv[r] = (rr < n) ? dinv[rr] : 0.f;
        }
#pragma unroll
        for (int t = 0; t < 3; ++t) {
            int col = t * 16 + lr;
            if (col < NCLASS) {
#pragma unroll
                for (int r = 0; r < 4; ++r) {
                    int rr = r0 + r;
                    if (rr < n)
                        H2[(size_t)rr * NCLASS + col] =
                            (_Float16)((acc[t][r] + b2v[t]) * dv[r]);
                }
            }
        }
    }
}

// ---------------------------------------------------------------------------
// agg2 + log_softmax -> out. Gathers COMPACT 40-col H2 rows (80 B):
// lanes m<10 load half4; m>=10 idle. 32-bit shift-add addressing.
// ---------------------------------------------------------------------------
__global__ __launch_bounds__(256) void agg2_lsm_kernel(
    const int* __restrict__ es, const int* __restrict__ row_start,
    const float* __restrict__ dinv, const _Float16* __restrict__ H2,
    float* __restrict__ out, int n) {
    int wave = threadIdx.x >> 6;
    int lane = threadIdx.x & 63;
    int q = lane >> 4;
    int m = lane & 15;
    bool valid = (m < 10);
    int stride = gridDim.x * 4;
    for (int node = blockIdx.x * 4 + wave; node < n; node += stride) {
        int e0 = row_start[node], e1 = row_start[node + 1];
        float a0 = 0.f, a1 = 0.f, a2 = 0.f, a3 = 0.f;
        for (int e = e0; e < e1; e += 64) {
            int cnt = e1 - e; if (cnt > 64) cnt = 64;
            int myE = es[e + ((lane < cnt) ? lane : 0)];
            for (int j = 0; j < cnt; j += 16) {
#pragma unroll
                for (int p = 0; p < 4; ++p) {
                    int jj = j + 4 * p + q;
                    int rr = __shfl(myE, jj, 64);
                    if (valid && jj < cnt) {
                        int off = (((rr << 2) + rr) << 3) + (m << 2);  // rr*40 + 4m
                        half4_t v = *(const half4_t*)(H2 + off);
                        a0 += (float)v[0]; a1 += (float)v[1];
                        a2 += (float)v[2]; a3 += (float)v[3];
                    }
                }
            }
        }
        if (q == 0 && valid) {  // self-loop
            int off = (((node << 2) + node) << 3) + (m << 2);
            half4_t v = *(const half4_t*)(H2 + off);
            a0 += (float)v[0]; a1 += (float)v[1];
            a2 += (float)v[2]; a3 += (float)v[3];
        }
        a0 += __shfl_xor(a0, 16, 64); a0 += __shfl_xor(a0, 32, 64);
        a1 += __shfl_xor(a1, 16, 64); a1 += __shfl_xor(a1, 32, 64);
        a2 += __shfl_xor(a2, 16, 64); a2 += __shfl_xor(a2, 32, 64);
        a3 += __shfl_xor(a3, 16, 64); a3 += __shfl_xor(a3, 32, 64);
        float di = dinv[node];
        float v0 = a0 * di, v1 = a1 * di, v2 = a2 * di, v3 = a3 * di;
        float vmax = valid ? fmaxf(fmaxf(v0, v1), fmaxf(v2, v3)) : -INFINITY;
#pragma unroll
        for (int off = 8; off; off >>= 1) vmax = fmaxf(vmax, __shfl_xor(vmax, off, 64));
        float sume = valid ? (__expf(v0 - vmax) + __expf(v1 - vmax) +
                              __expf(v2 - vmax) + __expf(v3 - vmax)) : 0.f;
#pragma unroll
        for (int off = 8; off; off >>= 1) sume += __shfl_xor(sume, off, 64);
        float lse = __logf(sume) + vmax;
        if (lane < 10) {
            float4 o = make_float4(v0 - lse, v1 - lse, v2 - lse, v3 - lse);
            *(float4*)(out + (size_t)node * NCLASS + 4 * lane) = o;
        }
    }
}

// ---------------------------------------------------------------------------
extern "C" void kernel_launch(void* const* d_in, const int* in_sizes, int n_in,
                              void* d_out, int out_size, void* d_ws, size_t ws_size,
                              hipStream_t stream) {
    const float* x  = (const float*)d_in[0];
    const int*   ei = (const int*)d_in[1];
    const float* W1 = (const float*)d_in[2];
    const float* b1 = (const float*)d_in[3];
    const float* W2 = (const float*)d_in[4];
    const float* b2 = (const float*)d_in[5];
    float* out = (float*)d_out;

    const int n = in_sizes[0] / NFEAT;       // 100000
    const int E = in_sizes[1] / 2;           // 1600000
    const int* src = ei;
    const int* dst = ei + E;
    const int nrange_h = (n + RANGE_H - 1) / RANGE_H;  // 4
    const int nrange_s = (n + RANGE_S - 1) / RANGE_S;  // 7

    // workspace layout. Aliasing (stream-ordered, safe):
    //   es   over deg_p  (deg_p dead after reduce)
    //   H2   over hist_p (hist_p dead after base)
    //   H1/AGG over bases (bases dead after scatter)
    char* ws = (char*)d_ws;
    float*          dinv      = (float*)(ws + 0);                     // 400 KB
    int*            htot      = (int*)(ws + (512 << 10));
    int*            scanned   = (int*)(ws + (1024 << 10));
    int*            row_start = (int*)(ws + (1536 << 10));
    int*            bsums     = (int*)(ws + (2048 << 10));
    unsigned short* deg_p     = (unsigned short*)(ws + (3u << 20));   // 12.8 MB [3,15.8)
    unsigned short* hist_p    = (unsigned short*)(ws + (16u << 20));  // 12.8 MB [16,28.8)
    int*            bases     = (int*)(ws + (29u << 20));             // 25.6 MB [29,54.6)
    int*            es        = (int*)(ws + (3u << 20));              // 6.4 MB  (alias deg_p)
    _Float16*       H2        = (_Float16*)(ws + (16u << 20));        // 8 MB    (alias hist_p)
    _Float16*       H1        = (_Float16*)(ws + (29u << 20));        // 12.8 MB (alias bases)
    _Float16*       AGG       = (_Float16*)(ws + (42u << 20));        // 12.8 MB (alias bases)

    const int blk = 256;
    const int nblk_n = (n + blk - 1) / blk;  // 391

    histdeg_kernel<<<NCHUNK * nrange_h, 1024, 0, stream>>>(src, dst, E, n, nrange_h,
                                                           deg_p, hist_p);
    reduce_kernel<<<nblk_n, blk, 0, stream>>>(deg_p, hist_p, dinv, htot, n);

    scan_block_kernel<<<nblk_n, blk, 0, stream>>>(htot, scanned, bsums, n);
    scan_partials_kernel<<<1, 512, 0, stream>>>(bsums, nblk_n);
    scan_add_kernel<<<nblk_n, blk, 0, stream>>>(scanned, bsums, row_start, n, E);
    base_kernel<<<nblk_n, blk, 0, stream>>>(row_start, hist_p, bases, n);

    scatter_kernel<<<NCHUNK * nrange_s, 1024, 0, stream>>>(src, dst, E, n, nrange_s,
                                                           bases, es);

    gemm1_mfma_kernel<<<512, blk, 0, stream>>>(x, W1, b1, dinv, H1, n);

    agg1_kernel<<<4096, blk, 0, stream>>>(es, row_start, dinv, H1, AGG, n);

    gemm2_mfma_kernel<<<512, blk, 0, stream>>>(AGG, W2, b2, dinv, H2, n);

    agg2_lsm_kernel<<<4096, blk, 0, stream>>>(es, row_start, dinv, H2, out, n);
}

// Round 9
// 302.439 us; speedup vs baseline: 2.0054x; 1.0130x over previous
//
#include <hip/hip_runtime.h>
#include <hip/hip_fp8.h>
#include <math.h>

#define NFEAT 128
#define NHID 64
#define NCLASS 40
#define NCHUNK 64
#define RANGE_H 32768 // histdeg LDS range (128 KiB LDS, 4 ranges cover 100k)
#define RANGE_S 16384 // scatter LDS range (64 KiB cursors, 7 ranges)

typedef _Float16 half4_t __attribute__((ext_vector_type(4)));
typedef _Float16 half8_t __attribute__((ext_vector_type(8)));
typedef float f32x4 __attribute__((ext_vector_type(4)));

__device__ __forceinline__ float fp8f(unsigned b) {
    __hip_fp8_e4m3 h;
    h.__x = (__hip_fp8_storage_t)b;
    return (float)h;
}

// ---------------------------------------------------------------------------
// LDS-binned deg(src) + hist(dst), packed 2xu16 counters, no global atomics.
// ---------------------------------------------------------------------------
__global__ __launch_bounds__(1024) void histdeg_kernel(
    const int* __restrict__ src, const int* __restrict__ dst, int E, int n,
    int nrange, unsigned short* __restrict__ deg_p,
    unsigned short* __restrict__ hist_p) {
    __shared__ unsigned int degc[RANGE_H / 2];   // 64 KB
    __shared__ unsigned int histc[RANGE_H / 2];  // 64 KB
    int c = blockIdx.x / nrange;
    int r = blockIdx.x - c * nrange;
    int r0 = r * RANGE_H;
    for (int i = threadIdx.x; i < RANGE_H / 2; i += 1024) {
        degc[i] = 0u;
        histc[i] = 0u;
    }
    __syncthreads();
    int e0 = (int)((long long)E * c / NCHUNK);
    int e1 = (int)((long long)E * (c + 1) / NCHUNK);
    for (int e = e0 + threadIdx.x * 4; e + 4 <= e1; e += 4096) {
        int4 s4 = *(const int4*)(src + e);
        int4 d4 = *(const int4*)(dst + e);
        int ss[4] = {s4.x, s4.y, s4.z, s4.w};
        int dd[4] = {d4.x, d4.y, d4.z, d4.w};
#pragma unroll
        for (int k = 0; k < 4; ++k) {
            int s = ss[k] - r0, d = dd[k] - r0;
            if ((unsigned)s < (unsigned)RANGE_H)
                atomicAdd(&degc[s >> 1], 1u << ((s & 1) * 16));
            if ((unsigned)d < (unsigned)RANGE_H)
                atomicAdd(&histc[d >> 1], 1u << ((d & 1) * 16));
        }
    }
    int tb = e0 + ((e1 - e0) & ~3);  // scalar tail
    for (int e = tb + threadIdx.x; e < e1; e += 1024) {
        int s = src[e] - r0, d = dst[e] - r0;
        if ((unsigned)s < (unsigned)RANGE_H)
            atomicAdd(&degc[s >> 1], 1u << ((s & 1) * 16));
        if ((unsigned)d < (unsigned)RANGE_H)
            atomicAdd(&histc[d >> 1], 1u << ((d & 1) * 16));
    }
    __syncthreads();
    int hi = n - r0; if (hi > RANGE_H) hi = RANGE_H;
    for (int i = threadIdx.x; i < hi; i += 1024) {
        unsigned dv = (degc[i >> 1] >> ((i & 1) * 16)) & 0xFFFFu;
        unsigned hv = (histc[i >> 1] >> ((i & 1) * 16)) & 0xFFFFu;
        deg_p[(size_t)c * n + r0 + i] = (unsigned short)dv;
        hist_p[(size_t)c * n + r0 + i] = (unsigned short)hv;
    }
}

// deg = 1 + sum_c deg_p ; dinv = rsqrt(deg) ; htot = sum_c hist_p
__global__ void reduce_kernel(const unsigned short* __restrict__ deg_p,
                              const unsigned short* __restrict__ hist_p,
                              float* __restrict__ dinv,
                              int* __restrict__ htot, int n) {
    int i = blockIdx.x * blockDim.x + threadIdx.x;
    if (i >= n) return;
    int d = 1, h = 0;
#pragma unroll 8
    for (int c = 0; c < NCHUNK; ++c) {
        d += deg_p[(size_t)c * n + i];
        h += hist_p[(size_t)c * n + i];
    }
    dinv[i] = rsqrtf((float)d);
    htot[i] = h;
}

// ---------------------------------------------------------------------------
// exclusive scan of htot[n] -> row_start[n+1]  (3 kernels)
// ---------------------------------------------------------------------------
__global__ void scan_block_kernel(const int* __restrict__ hist,
                                  int* __restrict__ scanned,
                                  int* __restrict__ bsums, int n) {
    __shared__ int tmp[256];
    int i = blockIdx.x * 256 + threadIdx.x;
    int v = (i < n) ? hist[i] : 0;
    tmp[threadIdx.x] = v;
    __syncthreads();
#pragma unroll
    for (int off = 1; off < 256; off <<= 1) {
        int t = (threadIdx.x >= off) ? tmp[threadIdx.x - off] : 0;
        __syncthreads();
        tmp[threadIdx.x] += t;
        __syncthreads();
    }
    if (i < n) scanned[i] = tmp[threadIdx.x] - v;  // exclusive
    if (threadIdx.x == 255) bsums[blockIdx.x] = tmp[255];
}

__global__ void scan_partials_kernel(int* __restrict__ bsums, int nb) {
    __shared__ int tmp[512];
    int v = (threadIdx.x < nb) ? bsums[threadIdx.x] : 0;
    tmp[threadIdx.x] = v;
    __syncthreads();
#pragma unroll
    for (int off = 1; off < 512; off <<= 1) {
        int t = (threadIdx.x >= off) ? tmp[threadIdx.x - off] : 0;
        __syncthreads();
        tmp[threadIdx.x] += t;
        __syncthreads();
    }
    if (threadIdx.x < nb) bsums[threadIdx.x] = tmp[threadIdx.x] - v;  // exclusive
}

__global__ void scan_add_kernel(const int* __restrict__ scanned,
                                const int* __restrict__ bsums,
                                int* __restrict__ row_start, int n, int E) {
    int i = blockIdx.x * 256 + threadIdx.x;
    if (i < n) row_start[i] = scanned[i] + bsums[blockIdx.x];
    if (i == 0) row_start[n] = E;
}

// per-chunk cursor bases: bases[c][i] = row_start[i] + sum_{t<c} hist_p[t][i]
__global__ void base_kernel(const int* __restrict__ row_start,
                            const unsigned short* __restrict__ hist_p,
                            int* __restrict__ bases, int n) {
    int i = blockIdx.x * blockDim.x + threadIdx.x;
    if (i >= n) return;
    int r = row_start[i];
#pragma unroll 8
    for (int c = 0; c < NCHUNK; ++c) {
        bases[(size_t)c * n + i] = r;
        r += hist_p[(size_t)c * n + i];
    }
}

// ---------------------------------------------------------------------------
// scatter: counting-sort edge srcs by dst; cursors in LDS; int4 edge loads.
// ---------------------------------------------------------------------------
__global__ __launch_bounds__(1024) void scatter_kernel(
    const int* __restrict__ src, const int* __restrict__ dst, int E, int n,
    int nrange, const int* __restrict__ bases, int* __restrict__ es) {
    __shared__ int cur[RANGE_S];  // 64 KB
    int c = blockIdx.x / nrange;
    int r = blockIdx.x - c * nrange;
    int r0 = r * RANGE_S;
    int hi = n - r0; if (hi > RANGE_S) hi = RANGE_S;
    for (int i = threadIdx.x; i < hi; i += 1024)
        cur[i] = bases[(size_t)c * n + r0 + i];
    __syncthreads();
    int e0 = (int)((long long)E * c / NCHUNK);
    int e1 = (int)((long long)E * (c + 1) / NCHUNK);
    for (int e = e0 + threadIdx.x * 4; e + 4 <= e1; e += 4096) {
        int4 s4 = *(const int4*)(src + e);
        int4 d4 = *(const int4*)(dst + e);
        int ss[4] = {s4.x, s4.y, s4.z, s4.w};
        int dd[4] = {d4.x, d4.y, d4.z, d4.w};
#pragma unroll
        for (int k = 0; k < 4; ++k) {
            int d = dd[k] - r0;
            if ((unsigned)d < (unsigned)hi) {
                int pos = atomicAdd(&cur[d], 1);
                es[pos] = ss[k];
            }
        }
    }
    int tb = e0 + ((e1 - e0) & ~3);  // scalar tail
    for (int e = tb + threadIdx.x; e < e1; e += 1024) {
        int d = dst[e] - r0;
        if ((unsigned)d < (unsigned)hi) {
            int pos = atomicAdd(&cur[d], 1);
            es[pos] = src[e];
        }
    }
}

// ---------------------------------------------------------------------------
// gemm1 (MFMA): H1' = dinv * (x @ W1 + b1), stored FP8 e4m3, 64-B rows
// (one cache line per row -> 1 line per edge-gather in agg1).
// ---------------------------------------------------------------------------
__global__ __launch_bounds__(256) void gemm1_mfma_kernel(
    const float* __restrict__ x, const float* __restrict__ W1,
    const float* __restrict__ b1, const float* __restrict__ dinv,
    unsigned char* __restrict__ H1f8, int n) {
    int wave = threadIdx.x >> 6;
    int lane = threadIdx.x & 63;
    int lr = lane & 15;
    int kg = lane >> 4;
    half8_t bf[4][4];
    float b1v[4];
#pragma unroll
    for (int t = 0; t < 4; ++t) {
        int col = t * 16 + lr;
        b1v[t] = b1[col];
#pragma unroll
        for (int ks = 0; ks < 4; ++ks) {
            int kb = ks * 32 + kg * 8;
            half8_t hb;
#pragma unroll
            for (int j = 0; j < 8; ++j) hb[j] = (_Float16)W1[(kb + j) * NHID + col];
            bf[ks][t] = hb;
        }
    }
    int nt16 = (n + 15) >> 4;
    for (int gt = blockIdx.x * 4 + wave; gt < nt16; gt += gridDim.x * 4) {
        int m0 = gt * 16;
        int arow = m0 + lr; if (arow >= n) arow = n - 1;
        f32x4 acc[4] = {f32x4{0,0,0,0}, f32x4{0,0,0,0}, f32x4{0,0,0,0}, f32x4{0,0,0,0}};
#pragma unroll
        for (int ks = 0; ks < 4; ++ks) {
            const float* ap = x + (size_t)arow * NFEAT + ks * 32 + kg * 8;
            float4 a0 = *(const float4*)ap;
            float4 a1 = *(const float4*)(ap + 4);
            half8_t af;
            af[0] = (_Float16)a0.x; af[1] = (_Float16)a0.y;
            af[2] = (_Float16)a0.z; af[3] = (_Float16)a0.w;
            af[4] = (_Float16)a1.x; af[5] = (_Float16)a1.y;
            af[6] = (_Float16)a1.z; af[7] = (_Float16)a1.w;
#pragma unroll
            for (int t = 0; t < 4; ++t)
                acc[t] = __builtin_amdgcn_mfma_f32_16x16x32_f16(af, bf[ks][t], acc[t], 0, 0, 0);
        }
        int r0 = m0 + kg * 4;
        float dv[4];
#pragma unroll
        for (int r = 0; r < 4; ++r) {
            int rr = r0 + r;
            dv[r] = (rr < n) ? dinv[rr] : 0.f;
        }
#pragma unroll
        for (int t = 0; t < 4; ++t)
#pragma unroll
            for (int r = 0; r < 4; ++r) {
                int rr = r0 + r;
                if (rr < n) {
                    __hip_fp8_e4m3 q((acc[t][r] + b1v[t]) * dv[r]);
                    H1f8[((size_t)rr << 6) + t * 16 + lr] = (unsigned char)q.__x;
                }
            }
    }
}

// ---------------------------------------------------------------------------
// agg1: AGG[d] = relu(dinv[d] * (H1'[d] + sum_{s in N(d)} H1'[s])), fp16 out.
// Gathers FP8 rows: each 16-lane group loads one uint (4 fp8) -> 64 B/row.
// ---------------------------------------------------------------------------
__global__ __launch_bounds__(256) void agg1_kernel(
    const int* __restrict__ es, const int* __restrict__ row_start,
    const float* __restrict__ dinv, const unsigned char* __restrict__ H1f8,
    _Float16* __restrict__ AGG, int n) {
    int wave = threadIdx.x >> 6;
    int lane = threadIdx.x & 63;
    int q = lane >> 4;
    int m = lane & 15;
    int stride = gridDim.x * 4;
    for (int node = blockIdx.x * 4 + wave; node < n; node += stride) {
        int e0 = row_start[node], e1 = row_start[node + 1];
        float a0 = 0.f, a1 = 0.f, a2 = 0.f, a3 = 0.f;
        for (int e = e0; e < e1; e += 64) {
            int cnt = e1 - e; if (cnt > 64) cnt = 64;
            int myE = es[e + ((lane < cnt) ? lane : 0)];
            for (int j = 0; j < cnt; j += 16) {
#pragma unroll
                for (int p = 0; p < 4; ++p) {
                    int jj = j + 4 * p + q;
                    int rr = __shfl(myE, jj, 64);
                    if (jj < cnt) {
                        unsigned w = *(const unsigned*)(H1f8 + ((size_t)rr << 6) + (m << 2));
                        a0 += fp8f(w & 0xFFu);
                        a1 += fp8f((w >> 8) & 0xFFu);
                        a2 += fp8f((w >> 16) & 0xFFu);
                        a3 += fp8f(w >> 24);
                    }
                }
            }
        }
        if (q == 0) {  // self-loop, counted once
            unsigned w = *(const unsigned*)(H1f8 + ((size_t)node << 6) + (m << 2));
            a0 += fp8f(w & 0xFFu);
            a1 += fp8f((w >> 8) & 0xFFu);
            a2 += fp8f((w >> 16) & 0xFFu);
            a3 += fp8f(w >> 24);
        }
        a0 += __shfl_xor(a0, 16, 64); a0 += __shfl_xor(a0, 32, 64);
        a1 += __shfl_xor(a1, 16, 64); a1 += __shfl_xor(a1, 32, 64);
        a2 += __shfl_xor(a2, 16, 64); a2 += __shfl_xor(a2, 32, 64);
        a3 += __shfl_xor(a3, 16, 64); a3 += __shfl_xor(a3, 32, 64);
        float di = dinv[node];
        if (lane < 16) {
            half4_t o;
            o[0] = (_Float16)fmaxf(a0 * di, 0.f);
            o[1] = (_Float16)fmaxf(a1 * di, 0.f);
            o[2] = (_Float16)fmaxf(a2 * di, 0.f);
            o[3] = (_Float16)fmaxf(a3 * di, 0.f);
            *(half4_t*)(AGG + ((size_t)node << 6) + (lane << 2)) = o;
        }
    }
}

// ---------------------------------------------------------------------------
// gemm2 (MFMA): H2' = dinv * (AGG @ W2 + b2), fp16, SPLIT storage:
// H2a[n][32] (cols 0..31, 64-B aligned rows) + H2b[n][8] (cols 32..39, 16 B).
// ---------------------------------------------------------------------------
__global__ __launch_bounds__(256) void gemm2_mfma_kernel(
    const _Float16* __restrict__ AGG, const float* __restrict__ W2,
    const float* __restrict__ b2, const float* __restrict__ dinv,
    _Float16* __restrict__ H2a, _Float16* __restrict__ H2b, int n) {
    int wave = threadIdx.x >> 6;
    int lane = threadIdx.x & 63;
    int lr = lane & 15;
    int kg = lane >> 4;
    half8_t bf[2][3];
    float b2v[3];
#pragma unroll
    for (int t = 0; t < 3; ++t) {
        int col = t * 16 + lr;
        b2v[t] = (col < NCLASS) ? b2[col] : 0.f;
#pragma unroll
        for (int ks = 0; ks < 2; ++ks) {
            int kb = ks * 32 + kg * 8;
            half8_t hb;
#pragma unroll
            for (int j = 0; j < 8; ++j)
                hb[j] = (col < NCLASS) ? (_Float16)W2[(kb + j) * NCLASS + col]
                                       : (_Float16)0.f;
            bf[ks][t] = hb;
        }
    }
    int nt16 = (n + 15) >> 4;
    for (int gt = blockIdx.x * 4 + wave; gt < nt16; gt += gridDim.x * 4) {
        int m0 = gt * 16;
        int arow = m0 + lr; if (arow >= n) arow = n - 1;
        f32x4 acc[3] = {f32x4{0,0,0,0}, f32x4{0,0,0,0}, f32x4{0,0,0,0}};
#pragma unroll
        for (int ks = 0; ks < 2; ++ks) {
            half8_t af = *(const half8_t*)(AGG + ((size_t)arow << 6) + ks * 32 + kg * 8);
#pragma unroll
            for (int t = 0; t < 3; ++t)
                acc[t] = __builtin_amdgcn_mfma_f32_16x16x32_f16(af, bf[ks][t], acc[t], 0, 0, 0);
        }
        int r0 = m0 + kg * 4;
        float dv[4];
#pragma unroll
        for (int r = 0; r < 4; ++r) {
            int rr = r0 + r;
            dv[r] = (rr < n) ? dinv[rr] : 0.f;
        }
#pragma unroll
        for (int t = 0; t < 3; ++t) {
            int col = t * 16 + lr;
#pragma unroll
            for (int r = 0; r < 4; ++r) {
                int rr = r0 + r;
                if (rr < n) {
                    _Float16 val = (_Float16)((acc[t][r] + b2v[t]) * dv[r]);
                    if (col < 32)
                        H2a[((size_t)rr << 5) + col] = val;
                    else if (col < NCLASS)
                        H2b[((size_t)rr << 3) + (col - 32)] = val;
                }
            }
        }
    }
}

// ---------------------------------------------------------------------------
// agg2 + log_softmax -> out. Gathers split H2: quads m<8 read H2a (1 line per
// row), m=8,9 read H2b (1.6 MB, L2-resident). Packed fp16 accumulation.
// ---------------------------------------------------------------------------
__global__ __launch_bounds__(256) void agg2_lsm_kernel(
    const int* __restrict__ es, const int* __restrict__ row_start,
    const float* __restrict__ dinv, const _Float16* __restrict__ H2a,
    const _Float16* __restrict__ H2b, float* __restrict__ out, int n) {
    int wave = threadIdx.x >> 6;
    int lane = threadIdx.x & 63;
    int q = lane >> 4;
    int m = lane & 15;
    bool valid = (m < 10);
    int stride = gridDim.x * 4;
    for (int node = blockIdx.x * 4 + wave; node < n; node += stride) {
        int e0 = row_start[node], e1 = row_start[node + 1];
        half4_t acc4 = {(_Float16)0, (_Float16)0, (_Float16)0, (_Float16)0};
        for (int e = e0; e < e1; e += 64) {
            int cnt = e1 - e; if (cnt > 64) cnt = 64;
            int myE = es[e + ((lane < cnt) ? lane : 0)];
            for (int j = 0; j < cnt; j += 16) {
#pragma unroll
                for (int p = 0; p < 4; ++p) {
                    int jj = j + 4 * p + q;
                    int rr = __shfl(myE, jj, 64);
                    if (valid && jj < cnt) {
                        const _Float16* ptr = (m < 8)
                            ? H2a + (((size_t)rr << 5) + (m << 2))
                            : H2b + (((size_t)rr << 3) + ((m & 7) << 2));
                        acc4 += *(const half4_t*)ptr;
                    }
                }
            }
        }
        if (q == 0 && valid) {  // self-loop
            const _Float16* ptr = (m < 8)
                ? H2a + (((size_t)node << 5) + (m << 2))
                : H2b + (((size_t)node << 3) + ((m & 7) << 2));
            acc4 += *(const half4_t*)ptr;
        }
        // packed merge across lane^16 and lane^32
        union { half4_t h; int i[2]; } u, w;
        u.h = acc4;
        w.i[0] = __shfl_xor(u.i[0], 16, 64);
        w.i[1] = __shfl_xor(u.i[1], 16, 64);
        u.h += w.h;
        w.i[0] = __shfl_xor(u.i[0], 32, 64);
        w.i[1] = __shfl_xor(u.i[1], 32, 64);
        u.h += w.h;
        float di = dinv[node];
        float v0 = (float)u.h[0] * di, v1 = (float)u.h[1] * di;
        float v2 = (float)u.h[2] * di, v3 = (float)u.h[3] * di;
        float vmax = valid ? fmaxf(fmaxf(v0, v1), fmaxf(v2, v3)) : -INFINITY;
#pragma unroll
        for (int off = 8; off; off >>= 1) vmax = fmaxf(vmax, __shfl_xor(vmax, off, 64));
        float sume = valid ? (__expf(v0 - vmax) + __expf(v1 - vmax) +
                              __expf(v2 - vmax) + __expf(v3 - vmax)) : 0.f;
#pragma unroll
        for (int off = 8; off; off >>= 1) sume += __shfl_xor(sume, off, 64);
        float lse = __logf(sume) + vmax;
        if (lane < 10) {
            float4 o = make_float4(v0 - lse, v1 - lse, v2 - lse, v3 - lse);
            *(float4*)(out + (size_t)node * NCLASS + 4 * lane) = o;
        }
    }
}

// ---------------------------------------------------------------------------
extern "C" void kernel_launch(void* const* d_in, const int* in_sizes, int n_in,
                              void* d_out, int out_size, void* d_ws, size_t ws_size,
                              hipStream_t stream) {
    const float* x  = (const float*)d_in[0];
    const int*   ei = (const int*)d_in[1];
    const float* W1 = (const float*)d_in[2];
    const float* b1 = (const float*)d_in[3];
    const float* W2 = (const float*)d_in[4];
    const float* b2 = (const float*)d_in[5];
    float* out = (float*)d_out;

    const int n = in_sizes[0] / NFEAT;       // 100000
    const int E = in_sizes[1] / 2;           // 1600000
    const int* src = ei;
    const int* dst = ei + E;
    const int nrange_h = (n + RANGE_H - 1) / RANGE_H;  // 4
    const int nrange_s = (n + RANGE_S - 1) / RANGE_S;  // 7

    // workspace layout. Aliasing (stream-ordered, safe):
    //   es over deg_p (dead after reduce); H1f8/H2a/H2b over hist_p (dead
    //   after base); AGG over bases (dead after scatter).
    char* ws = (char*)d_ws;
    float*          dinv      = (float*)(ws + 0);                     // 400 KB
    int*            htot      = (int*)(ws + (512 << 10));
    int*            scanned   = (int*)(ws + (1024 << 10));
    int*            row_start = (int*)(ws + (1536 << 10));
    int*            bsums     = (int*)(ws + (2048 << 10));
    unsigned short* deg_p     = (unsigned short*)(ws + (3u << 20));   // 12.8 MB [3,15.8)
    unsigned short* hist_p    = (unsigned short*)(ws + (16u << 20));  // 12.8 MB [16,28.8)
    int*            bases     = (int*)(ws + (29u << 20));             // 25.6 MB [29,54.6)
    int*            es        = (int*)(ws + (3u << 20));              // 6.4 MB (alias deg_p)
    unsigned char*  H1f8      = (unsigned char*)(ws + (16u << 20));   // 6.4 MB (alias hist_p)
    _Float16*       H2a       = (_Float16*)(ws + (23u << 20));        // 6.4 MB
    _Float16*       H2b      = (_Float16*)(ws + (30u << 20));         // 1.6 MB
    _Float16*       AGG       = (_Float16*)(ws + (32u << 20));        // 12.8 MB (alias bases)

    const int blk = 256;
    const int nblk_n = (n + blk - 1) / blk;  // 391

    histdeg_kernel<<<NCHUNK * nrange_h, 1024, 0, stream>>>(src, dst, E, n, nrange_h,
                                                           deg_p, hist_p);
    reduce_kernel<<<nblk_n, blk, 0, stream>>>(deg_p, hist_p, dinv, htot, n);

    scan_block_kernel<<<nblk_n, blk, 0, stream>>>(htot, scanned, bsums, n);
    scan_partials_kernel<<<1, 512, 0, stream>>>(bsums, nblk_n);
    scan_add_kernel<<<nblk_n, blk, 0, stream>>>(scanned, bsums, row_start, n, E);
    base_kernel<<<nblk_n, blk, 0, stream>>>(row_start, hist_p, bases, n);

    scatter_kernel<<<NCHUNK * nrange_s, 1024, 0, stream>>>(src, dst, E, n, nrange_s,
                                                           bases, es);

    gemm1_mfma_kernel<<<512, blk, 0, stream>>>(x, W1, b1, dinv, H1f8, n);

    agg1_kernel<<<4096, blk, 0, stream>>>(es, row_start, dinv, H1f8, AGG, n);

    gemm2_mfma_kernel<<<512, blk, 0, stream>>>(AGG, W2, b2, dinv, H2a, H2b, n);

    agg2_lsm_kernel<<<4096, blk, 0, stream>>>(es, row_start, dinv, H2a, H2b, out, n);
}

// Round 10
// 261.646 us; speedup vs baseline: 2.3181x; 1.1559x over previous
//
#include <hip/hip_runtime.h>
#include <hip/hip_fp8.h>
#include <math.h>

#define NFEAT 128
#define NHID 64
#define NCLASS 40
#define NCHUNK 64
#define RANGE_H 32768 // histdeg LDS range (128 KiB LDS, 4 ranges cover 100k)
#define RANGE_S 16384 // scatter LDS range (64 KiB cursors, 7 ranges)

typedef _Float16 half4_t __attribute__((ext_vector_type(4)));
typedef _Float16 half8_t __attribute__((ext_vector_type(8)));
typedef float f32x4 __attribute__((ext_vector_type(4)));

__device__ __forceinline__ float fp8f(unsigned b) {
    __hip_fp8_e4m3 h;
    h.__x = (__hip_fp8_storage_t)(b & 0xFFu);
    return (float)h;
}

// ---------------------------------------------------------------------------
// LDS-binned deg(src) + hist(dst), packed 2xu16 counters, no global atomics.
// ---------------------------------------------------------------------------
__global__ __launch_bounds__(1024) void histdeg_kernel(
    const int* __restrict__ src, const int* __restrict__ dst, int E, int n,
    int nrange, unsigned short* __restrict__ deg_p,
    unsigned short* __restrict__ hist_p) {
    __shared__ unsigned int degc[RANGE_H / 2];   // 64 KB
    __shared__ unsigned int histc[RANGE_H / 2];  // 64 KB
    int c = blockIdx.x / nrange;
    int r = blockIdx.x - c * nrange;
    int r0 = r * RANGE_H;
    for (int i = threadIdx.x; i < RANGE_H / 2; i += 1024) {
        degc[i] = 0u;
        histc[i] = 0u;
    }
    __syncthreads();
    int e0 = (int)((long long)E * c / NCHUNK);
    int e1 = (int)((long long)E * (c + 1) / NCHUNK);
    for (int e = e0 + threadIdx.x * 4; e + 4 <= e1; e += 4096) {
        int4 s4 = *(const int4*)(src + e);
        int4 d4 = *(const int4*)(dst + e);
        int ss[4] = {s4.x, s4.y, s4.z, s4.w};
        int dd[4] = {d4.x, d4.y, d4.z, d4.w};
#pragma unroll
        for (int k = 0; k < 4; ++k) {
            int s = ss[k] - r0, d = dd[k] - r0;
            if ((unsigned)s < (unsigned)RANGE_H)
                atomicAdd(&degc[s >> 1], 1u << ((s & 1) * 16));
            if ((unsigned)d < (unsigned)RANGE_H)
                atomicAdd(&histc[d >> 1], 1u << ((d & 1) * 16));
        }
    }
    int tb = e0 + ((e1 - e0) & ~3);  // scalar tail
    for (int e = tb + threadIdx.x; e < e1; e += 1024) {
        int s = src[e] - r0, d = dst[e] - r0;
        if ((unsigned)s < (unsigned)RANGE_H)
            atomicAdd(&degc[s >> 1], 1u << ((s & 1) * 16));
        if ((unsigned)d < (unsigned)RANGE_H)
            atomicAdd(&histc[d >> 1], 1u << ((d & 1) * 16));
    }
    __syncthreads();
    int hi = n - r0; if (hi > RANGE_H) hi = RANGE_H;
    for (int i = threadIdx.x; i < hi; i += 1024) {
        unsigned dv = (degc[i >> 1] >> ((i & 1) * 16)) & 0xFFFFu;
        unsigned hv = (histc[i >> 1] >> ((i & 1) * 16)) & 0xFFFFu;
        deg_p[(size_t)c * n + r0 + i] = (unsigned short)dv;
        hist_p[(size_t)c * n + r0 + i] = (unsigned short)hv;
    }
}

// deg = 1 + sum_c deg_p ; dinv = rsqrt(deg) ; htot = sum_c hist_p
__global__ void reduce_kernel(const unsigned short* __restrict__ deg_p,
                              const unsigned short* __restrict__ hist_p,
                              float* __restrict__ dinv,
                              int* __restrict__ htot, int n) {
    int i = blockIdx.x * blockDim.x + threadIdx.x;
    if (i >= n) return;
    int d = 1, h = 0;
#pragma unroll 8
    for (int c = 0; c < NCHUNK; ++c) {
        d += deg_p[(size_t)c * n + i];
        h += hist_p[(size_t)c * n + i];
    }
    dinv[i] = rsqrtf((float)d);
    htot[i] = h;
}

// ---------------------------------------------------------------------------
// exclusive scan of htot[n] -> row_start[n+1]  (3 kernels)
// ---------------------------------------------------------------------------
__global__ void scan_block_kernel(const int* __restrict__ hist,
                                  int* __restrict__ scanned,
                                  int* __restrict__ bsums, int n) {
    __shared__ int tmp[256];
    int i = blockIdx.x * 256 + threadIdx.x;
    int v = (i < n) ? hist[i] : 0;
    tmp[threadIdx.x] = v;
    __syncthreads();
#pragma unroll
    for (int off = 1; off < 256; off <<= 1) {
        int t = (threadIdx.x >= off) ? tmp[threadIdx.x - off] : 0;
        __syncthreads();
        tmp[threadIdx.x] += t;
        __syncthreads();
    }
    if (i < n) scanned[i] = tmp[threadIdx.x] - v;  // exclusive
    if (threadIdx.x == 255) bsums[blockIdx.x] = tmp[255];
}

__global__ void scan_partials_kernel(int* __restrict__ bsums, int nb) {
    __shared__ int tmp[512];
    int v = (threadIdx.x < nb) ? bsums[threadIdx.x] : 0;
    tmp[threadIdx.x] = v;
    __syncthreads();
#pragma unroll
    for (int off = 1; off < 512; off <<= 1) {
        int t = (threadIdx.x >= off) ? tmp[threadIdx.x - off] : 0;
        __syncthreads();
        tmp[threadIdx.x] += t;
        __syncthreads();
    }
    if (threadIdx.x < nb) bsums[threadIdx.x] = tmp[threadIdx.x] - v;  // exclusive
}

__global__ void scan_add_kernel(const int* __restrict__ scanned,
                                const int* __restrict__ bsums,
                                int* __restrict__ row_start, int n, int E) {
    int i = blockIdx.x * 256 + threadIdx.x;
    if (i < n) row_start[i] = scanned[i] + bsums[blockIdx.x];
    if (i == 0) row_start[n] = E;
}

// per-chunk cursor bases: bases[c][i] = row_start[i] + sum_{t<c} hist_p[t][i]
__global__ void base_kernel(const int* __restrict__ row_start,
                            const unsigned short* __restrict__ hist_p,
                            int* __restrict__ bases, int n) {
    int i = blockIdx.x * blockDim.x + threadIdx.x;
    if (i >= n) return;
    int r = row_start[i];
#pragma unroll 8
    for (int c = 0; c < NCHUNK; ++c) {
        bases[(size_t)c * n + i] = r;
        r += hist_p[(size_t)c * n + i];
    }
}

// ---------------------------------------------------------------------------
// scatter: counting-sort edge srcs by dst; cursors in LDS; int4 edge loads.
// ---------------------------------------------------------------------------
__global__ __launch_bounds__(1024) void scatter_kernel(
    const int* __restrict__ src, const int* __restrict__ dst, int E, int n,
    int nrange, const int* __restrict__ bases, int* __restrict__ es) {
    __shared__ int cur[RANGE_S];  // 64 KB
    int c = blockIdx.x / nrange;
    int r = blockIdx.x - c * nrange;
    int r0 = r * RANGE_S;
    int hi = n - r0; if (hi > RANGE_S) hi = RANGE_S;
    for (int i = threadIdx.x; i < hi; i += 1024)
        cur[i] = bases[(size_t)c * n + r0 + i];
    __syncthreads();
    int e0 = (int)((long long)E * c / NCHUNK);
    int e1 = (int)((long long)E * (c + 1) / NCHUNK);
    for (int e = e0 + threadIdx.x * 4; e + 4 <= e1; e += 4096) {
        int4 s4 = *(const int4*)(src + e);
        int4 d4 = *(const int4*)(dst + e);
        int ss[4] = {s4.x, s4.y, s4.z, s4.w};
        int dd[4] = {d4.x, d4.y, d4.z, d4.w};
#pragma unroll
        for (int k = 0; k < 4; ++k) {
            int d = dd[k] - r0;
            if ((unsigned)d < (unsigned)hi) {
                int pos = atomicAdd(&cur[d], 1);
                es[pos] = ss[k];
            }
        }
    }
    int tb = e0 + ((e1 - e0) & ~3);  // scalar tail
    for (int e = tb + threadIdx.x; e < e1; e += 1024) {
        int d = dst[e] - r0;
        if ((unsigned)d < (unsigned)hi) {
            int pos = atomicAdd(&cur[d], 1);
            es[pos] = src[e];
        }
    }
}

// ---------------------------------------------------------------------------
// gemm1 (MFMA): H1' = dinv * (x @ W1 + b1), stored FP8 e4m3, 64-B rows.
// ---------------------------------------------------------------------------
__global__ __launch_bounds__(256) void gemm1_mfma_kernel(
    const float* __restrict__ x, const float* __restrict__ W1,
    const float* __restrict__ b1, const float* __restrict__ dinv,
    unsigned char* __restrict__ H1f8, int n) {
    int wave = threadIdx.x >> 6;
    int lane = threadIdx.x & 63;
    int lr = lane & 15;
    int kg = lane >> 4;
    half8_t bf[4][4];
    float b1v[4];
#pragma unroll
    for (int t = 0; t < 4; ++t) {
        int col = t * 16 + lr;
        b1v[t] = b1[col];
#pragma unroll
        for (int ks = 0; ks < 4; ++ks) {
            int kb = ks * 32 + kg * 8;
            half8_t hb;
#pragma unroll
            for (int j = 0; j < 8; ++j) hb[j] = (_Float16)W1[(kb + j) * NHID + col];
            bf[ks][t] = hb;
        }
    }
    int nt16 = (n + 15) >> 4;
    for (int gt = blockIdx.x * 4 + wave; gt < nt16; gt += gridDim.x * 4) {
        int m0 = gt * 16;
        int arow = m0 + lr; if (arow >= n) arow = n - 1;
        f32x4 acc[4] = {f32x4{0,0,0,0}, f32x4{0,0,0,0}, f32x4{0,0,0,0}, f32x4{0,0,0,0}};
#pragma unroll
        for (int ks = 0; ks < 4; ++ks) {
            const float* ap = x + (size_t)arow * NFEAT + ks * 32 + kg * 8;
            float4 a0 = *(const float4*)ap;
            float4 a1 = *(const float4*)(ap + 4);
            half8_t af;
            af[0] = (_Float16)a0.x; af[1] = (_Float16)a0.y;
            af[2] = (_Float16)a0.z; af[3] = (_Float16)a0.w;
            af[4] = (_Float16)a1.x; af[5] = (_Float16)a1.y;
            af[6] = (_Float16)a1.z; af[7] = (_Float16)a1.w;
#pragma unroll
            for (int t = 0; t < 4; ++t)
                acc[t] = __builtin_amdgcn_mfma_f32_16x16x32_f16(af, bf[ks][t], acc[t], 0, 0, 0);
        }
        int r0 = m0 + kg * 4;
        float dv[4];
#pragma unroll
        for (int r = 0; r < 4; ++r) {
            int rr = r0 + r;
            dv[r] = (rr < n) ? dinv[rr] : 0.f;
        }
#pragma unroll
        for (int t = 0; t < 4; ++t)
#pragma unroll
            for (int r = 0; r < 4; ++r) {
                int rr = r0 + r;
                if (rr < n) {
                    __hip_fp8_e4m3 q((acc[t][r] + b1v[t]) * dv[r]);
                    H1f8[((size_t)rr << 6) + t * 16 + lr] = (unsigned char)q.__x;
                }
            }
    }
}

// ---------------------------------------------------------------------------
// agg1: AGG[d] = relu(dinv[d]*(H1'[d] + sum_{s in N(d)} H1'[s])), fp16 out.
// QUAD-PER-NODE: 16-lane quad owns one node; lane m holds cols 4m..4m+3.
// 4-deep jj unroll -> 16 independent line-gathers in flight per wave.
// ---------------------------------------------------------------------------
__global__ __launch_bounds__(256) void agg1_kernel(
    const int* __restrict__ es, const int* __restrict__ row_start,
    const float* __restrict__ dinv, const unsigned char* __restrict__ H1f8,
    _Float16* __restrict__ AGG, int n) {
    int wave = threadIdx.x >> 6;
    int lane = threadIdx.x & 63;
    int g = lane >> 4;   // quad id (node slot)
    int m = lane & 15;   // feature quad
    int stride = gridDim.x * 16;
    for (int node = blockIdx.x * 16 + wave * 4 + g; node < n; node += stride) {
        int e0 = row_start[node];
        int cnt = row_start[node + 1] - e0;
        // self-loop init
        unsigned w = *(const unsigned*)(H1f8 + ((size_t)node << 6) + (m << 2));
        float a0 = fp8f(w), a1 = fp8f(w >> 8), a2 = fp8f(w >> 16), a3 = fp8f(w >> 24);
        for (int j = 0; j < cnt; j += 16) {
            int rem = cnt - j;
            int chunk = rem < 16 ? rem : 16;
            int myE = es[e0 + j + ((m < rem) ? m : 0)];
            int jj = 0;
            for (; jj + 4 <= chunk; jj += 4) {
                int r0 = __shfl(myE, (g << 4) + jj, 64);
                int r1 = __shfl(myE, (g << 4) + jj + 1, 64);
                int r2 = __shfl(myE, (g << 4) + jj + 2, 64);
                int r3 = __shfl(myE, (g << 4) + jj + 3, 64);
                unsigned w0 = *(const unsigned*)(H1f8 + ((size_t)r0 << 6) + (m << 2));
                unsigned w1 = *(const unsigned*)(H1f8 + ((size_t)r1 << 6) + (m << 2));
                unsigned w2 = *(const unsigned*)(H1f8 + ((size_t)r2 << 6) + (m << 2));
                unsigned w3 = *(const unsigned*)(H1f8 + ((size_t)r3 << 6) + (m << 2));
                a0 += fp8f(w0) + fp8f(w1) + fp8f(w2) + fp8f(w3);
                a1 += fp8f(w0 >> 8) + fp8f(w1 >> 8) + fp8f(w2 >> 8) + fp8f(w3 >> 8);
                a2 += fp8f(w0 >> 16) + fp8f(w1 >> 16) + fp8f(w2 >> 16) + fp8f(w3 >> 16);
                a3 += fp8f(w0 >> 24) + fp8f(w1 >> 24) + fp8f(w2 >> 24) + fp8f(w3 >> 24);
            }
            for (; jj < chunk; ++jj) {
                int rr = __shfl(myE, (g << 4) + jj, 64);
                unsigned ww = *(const unsigned*)(H1f8 + ((size_t)rr << 6) + (m << 2));
                a0 += fp8f(ww); a1 += fp8f(ww >> 8);
                a2 += fp8f(ww >> 16); a3 += fp8f(ww >> 24);
            }
        }
        float di = dinv[node];
        half4_t o;
        o[0] = (_Float16)fmaxf(a0 * di, 0.f);
        o[1] = (_Float16)fmaxf(a1 * di, 0.f);
        o[2] = (_Float16)fmaxf(a2 * di, 0.f);
        o[3] = (_Float16)fmaxf(a3 * di, 0.f);
        *(half4_t*)(AGG + ((size_t)node << 6) + (m << 2)) = o;
    }
}

// ---------------------------------------------------------------------------
// gemm2 (MFMA): H2' = dinv * (AGG @ W2 + b2), stored FP8 e4m3, 64-B rows
// (cols 0..39 used; pad bytes never read).
// ---------------------------------------------------------------------------
__global__ __launch_bounds__(256) void gemm2_mfma_kernel(
    const _Float16* __restrict__ AGG, const float* __restrict__ W2,
    const float* __restrict__ b2, const float* __restrict__ dinv,
    unsigned char* __restrict__ H2f8, int n) {
    int wave = threadIdx.x >> 6;
    int lane = threadIdx.x & 63;
    int lr = lane & 15;
    int kg = lane >> 4;
    half8_t bf[2][3];
    float b2v[3];
#pragma unroll
    for (int t = 0; t < 3; ++t) {
        int col = t * 16 + lr;
        b2v[t] = (col < NCLASS) ? b2[col] : 0.f;
#pragma unroll
        for (int ks = 0; ks < 2; ++ks) {
            int kb = ks * 32 + kg * 8;
            half8_t hb;
#pragma unroll
            for (int j = 0; j < 8; ++j)
                hb[j] = (col < NCLASS) ? (_Float16)W2[(kb + j) * NCLASS + col]
                                       : (_Float16)0.f;
            bf[ks][t] = hb;
        }
    }
    int nt16 = (n + 15) >> 4;
    for (int gt = blockIdx.x * 4 + wave; gt < nt16; gt += gridDim.x * 4) {
        int m0 = gt * 16;
        int arow = m0 + lr; if (arow >= n) arow = n - 1;
        f32x4 acc[3] = {f32x4{0,0,0,0}, f32x4{0,0,0,0}, f32x4{0,0,0,0}};
#pragma unroll
        for (int ks = 0; ks < 2; ++ks) {
            half8_t af = *(const half8_t*)(AGG + ((size_t)arow << 6) + ks * 32 + kg * 8);
#pragma unroll
            for (int t = 0; t < 3; ++t)
                acc[t] = __builtin_amdgcn_mfma_f32_16x16x32_f16(af, bf[ks][t], acc[t], 0, 0, 0);
        }
        int r0 = m0 + kg * 4;
        float dv[4];
#pragma unroll
        for (int r = 0; r < 4; ++r) {
            int rr = r0 + r;
            dv[r] = (rr < n) ? dinv[rr] : 0.f;
        }
#pragma unroll
        for (int t = 0; t < 3; ++t) {
            int col = t * 16 + lr;
            if (col < NCLASS) {
#pragma unroll
                for (int r = 0; r < 4; ++r) {
                    int rr = r0 + r;
                    if (rr < n) {
                        __hip_fp8_e4m3 q((acc[t][r] + b2v[t]) * dv[r]);
                        H2f8[((size_t)rr << 6) + col] = (unsigned char)q.__x;
                    }
                }
            }
        }
    }
}

// ---------------------------------------------------------------------------
// agg2 + log_softmax -> out. QUAD-PER-NODE over FP8 64-B rows (1 line/edge);
// lanes m<10 gather 4 bytes each; lsm reduces within the quad.
// ---------------------------------------------------------------------------
__global__ __launch_bounds__(256) void agg2_lsm_kernel(
    const int* __restrict__ es, const int* __restrict__ row_start,
    const float* __restrict__ dinv, const unsigned char* __restrict__ H2f8,
    float* __restrict__ out, int n) {
    int wave = threadIdx.x >> 6;
    int lane = threadIdx.x & 63;
    int g = lane >> 4;
    int m = lane & 15;
    bool valid = (m < 10);
    int stride = gridDim.x * 16;
    for (int node = blockIdx.x * 16 + wave * 4 + g; node < n; node += stride) {
        int e0 = row_start[node];
        int cnt = row_start[node + 1] - e0;
        float a0 = 0.f, a1 = 0.f, a2 = 0.f, a3 = 0.f;
        if (valid) {  // self-loop
            unsigned w = *(const unsigned*)(H2f8 + ((size_t)node << 6) + (m << 2));
            a0 = fp8f(w); a1 = fp8f(w >> 8); a2 = fp8f(w >> 16); a3 = fp8f(w >> 24);
        }
        for (int j = 0; j < cnt; j += 16) {
            int rem = cnt - j;
            int chunk = rem < 16 ? rem : 16;
            int myE = es[e0 + j + ((m < rem) ? m : 0)];
            int jj = 0;
            for (; jj + 4 <= chunk; jj += 4) {
                int r0 = __shfl(myE, (g << 4) + jj, 64);
                int r1 = __shfl(myE, (g << 4) + jj + 1, 64);
                int r2 = __shfl(myE, (g << 4) + jj + 2, 64);
                int r3 = __shfl(myE, (g << 4) + jj + 3, 64);
                if (valid) {
                    unsigned w0 = *(const unsigned*)(H2f8 + ((size_t)r0 << 6) + (m << 2));
                    unsigned w1 = *(const unsigned*)(H2f8 + ((size_t)r1 << 6) + (m << 2));
                    unsigned w2 = *(const unsigned*)(H2f8 + ((size_t)r2 << 6) + (m << 2));
                    unsigned w3 = *(const unsigned*)(H2f8 + ((size_t)r3 << 6) + (m << 2));
                    a0 += fp8f(w0) + fp8f(w1) + fp8f(w2) + fp8f(w3);
                    a1 += fp8f(w0 >> 8) + fp8f(w1 >> 8) + fp8f(w2 >> 8) + fp8f(w3 >> 8);
                    a2 += fp8f(w0 >> 16) + fp8f(w1 >> 16) + fp8f(w2 >> 16) + fp8f(w3 >> 16);
                    a3 += fp8f(w0 >> 24) + fp8f(w1 >> 24) + fp8f(w2 >> 24) + fp8f(w3 >> 24);
                }
            }
            for (; jj < chunk; ++jj) {
                int rr = __shfl(myE, (g << 4) + jj, 64);
                if (valid) {
                    unsigned ww = *(const unsigned*)(H2f8 + ((size_t)rr << 6) + (m << 2));
                    a0 += fp8f(ww); a1 += fp8f(ww >> 8);
                    a2 += fp8f(ww >> 16); a3 += fp8f(ww >> 24);
                }
            }
        }
        float di = dinv[node];
        float v0 = a0 * di, v1 = a1 * di, v2 = a2 * di, v3 = a3 * di;
        float vmax = valid ? fmaxf(fmaxf(v0, v1), fmaxf(v2, v3)) : -INFINITY;
#pragma unroll
        for (int off = 8; off; off >>= 1) vmax = fmaxf(vmax, __shfl_xor(vmax, off, 64));
        float sume = valid ? (__expf(v0 - vmax) + __expf(v1 - vmax) +
                              __expf(v2 - vmax) + __expf(v3 - vmax)) : 0.f;
#pragma unroll
        for (int off = 8; off; off >>= 1) sume += __shfl_xor(sume, off, 64);
        float lse = __logf(sume) + vmax;
        if (valid) {
            float4 o = make_float4(v0 - lse, v1 - lse, v2 - lse, v3 - lse);
            *(float4*)(out + (size_t)node * NCLASS + (m << 2)) = o;
        }
    }
}

// ---------------------------------------------------------------------------
extern "C" void kernel_launch(void* const* d_in, const int* in_sizes, int n_in,
                              void* d_out, int out_size, void* d_ws, size_t ws_size,
                              hipStream_t stream) {
    const float* x  = (const float*)d_in[0];
    const int*   ei = (const int*)d_in[1];
    const float* W1 = (const float*)d_in[2];
    const float* b1 = (const float*)d_in[3];
    const float* W2 = (const float*)d_in[4];
    const float* b2 = (const float*)d_in[5];
    float* out = (float*)d_out;

    const int n = in_sizes[0] / NFEAT;       // 100000
    const int E = in_sizes[1] / 2;           // 1600000
    const int* src = ei;
    const int* dst = ei + E;
    const int nrange_h = (n + RANGE_H - 1) / RANGE_H;  // 4
    const int nrange_s = (n + RANGE_S - 1) / RANGE_S;  // 7

    // workspace layout. Aliasing (stream-ordered, safe):
    //   es over deg_p (dead after reduce); H1f8/H2f8 over hist_p (dead after
    //   base); AGG over bases (dead after scatter).
    char* ws = (char*)d_ws;
    float*          dinv      = (float*)(ws + 0);                     // 400 KB
    int*            htot      = (int*)(ws + (512 << 10));
    int*            scanned   = (int*)(ws + (1024 << 10));
    int*            row_start = (int*)(ws + (1536 << 10));
    int*            bsums     = (int*)(ws + (2048 << 10));
    unsigned short* deg_p     = (unsigned short*)(ws + (3u << 20));   // 12.8 MB [3,15.8)
    unsigned short* hist_p    = (unsigned short*)(ws + (16u << 20));  // 12.8 MB [16,28.8)
    int*            bases     = (int*)(ws + (29u << 20));             // 25.6 MB [29,54.6)
    int*            es        = (int*)(ws + (3u << 20));              // 6.4 MB (alias deg_p)
    unsigned char*  H1f8      = (unsigned char*)(ws + (16u << 20));   // 6.4 MB (alias hist_p)
    unsigned char*  H2f8      = (unsigned char*)(ws + (23u << 20));   // 6.4 MB
    _Float16*       AGG       = (_Float16*)(ws + (32u << 20));        // 12.8 MB (alias bases)

    const int blk = 256;
    const int nblk_n = (n + blk - 1) / blk;  // 391

    histdeg_kernel<<<NCHUNK * nrange_h, 1024, 0, stream>>>(src, dst, E, n, nrange_h,
                                                           deg_p, hist_p);
    reduce_kernel<<<nblk_n, blk, 0, stream>>>(deg_p, hist_p, dinv, htot, n);

    scan_block_kernel<<<nblk_n, blk, 0, stream>>>(htot, scanned, bsums, n);
    scan_partials_kernel<<<1, 512, 0, stream>>>(bsums, nblk_n);
    scan_add_kernel<<<nblk_n, blk, 0, stream>>>(scanned, bsums, row_start, n, E);
    base_kernel<<<nblk_n, blk, 0, stream>>>(row_start, hist_p, bases, n);

    scatter_kernel<<<NCHUNK * nrange_s, 1024, 0, stream>>>(src, dst, E, n, nrange_s,
                                                           bases, es);

    gemm1_mfma_kernel<<<512, blk, 0, stream>>>(x, W1, b1, dinv, H1f8, n);

    agg1_kernel<<<4096, blk, 0, stream>>>(es, row_start, dinv, H1f8, AGG, n);

    gemm2_mfma_kernel<<<512, blk, 0, stream>>>(AGG, W2, b2, dinv, H2f8, n);

    agg2_lsm_kernel<<<4096, blk, 0, stream>>>(es, row_start, dinv, H2f8, out, n);
}